// Round 13
// baseline (682.869 us; speedup 1.0000x reference)
//
#include <hip/hip_runtime.h>
#include <math.h>

// SelfAttention B=4,S=2048,D=1024 fp32. Round 13: m97-geometry GEMMs.
// 128x128 tiles, 256 thr (4 waves 2x2), 48KB LDS (3 slots) -> 3 blocks/CU;
// r9-proven ledger unchanged: stage lead 2, counted vmcnt(4), one barrier
// per tile. Numerics identical to r11: split-bf16 proj (3-seg) -> 2-limb i8
// Q|K planes, i8 QKT (BK=64) -> split-bf16 L, bf16 P/V, f32 out.

typedef unsigned short u16;
typedef signed char s8;
typedef __attribute__((ext_vector_type(8))) short bf16x8;
typedef __attribute__((ext_vector_type(4))) float f32x4;
typedef __attribute__((ext_vector_type(4))) int i32x4;

__device__ __forceinline__ u16 f2bf(float x) {
  unsigned u = __float_as_uint(x);
  unsigned r = (u + 0x7fffu + ((u >> 16) & 1u)) >> 16;
  return (u16)r;
}
__device__ __forceinline__ float bf2f(u16 h) {
  return __uint_as_float((unsigned)h << 16);
}
__device__ __forceinline__ int clamp127(int q) {
  return q < -127 ? -127 : (q > 127 ? 127 : q);
}

__device__ __forceinline__ void gload_lds16(const void* g, void* l) {
  __builtin_amdgcn_global_load_lds(
      (const __attribute__((address_space(1))) unsigned int*)(g),
      (__attribute__((address_space(3))) unsigned int*)(l), 16, 0, 0);
}

template <int N>
__device__ __forceinline__ void wait_vmcnt() {
  if constexpr (N == 0) asm volatile("s_waitcnt vmcnt(0)" ::: "memory");
  else if constexpr (N == 4) asm volatile("s_waitcnt vmcnt(4)" ::: "memory");
}

// fp32 -> hi bf16 (+ optional lo bf16), grid-stride, vectorized
template <bool LO>
__global__ __launch_bounds__(256) void split_f32_kernel(
    const float* __restrict__ in, u16* __restrict__ hi, u16* __restrict__ lo,
    long long n) {
  long long i = ((long long)blockIdx.x * 256 + threadIdx.x) * 4;
  const long long step = (long long)gridDim.x * 256 * 4;
  for (; i < n; i += step) {
    float4 x = *(const float4*)(in + i);
    float xs[4] = {x.x, x.y, x.z, x.w};
    u16 hv[4], lv[4];
#pragma unroll
    for (int j = 0; j < 4; j++) {
      hv[j] = f2bf(xs[j]);
      if (LO) lv[j] = f2bf(xs[j] - bf2f(hv[j]));
    }
    ushort4 h;
    h.x = hv[0]; h.y = hv[1]; h.z = hv[2]; h.w = hv[3];
    *(ushort4*)(hi + i) = h;
    if (LO) {
      ushort4 l;
      l.x = lv[0]; l.y = lv[1]; l.z = lv[2]; l.w = lv[3];
      *(ushort4*)(lo + i) = l;
    }
  }
}

// ===== bf16 GEMM: NT over NSEG K-segments. BM=BN=128, BK=32, 256 thr =
// 4 waves (2M x 2N), wave tile 64x64 (acc[4][4]), 16 MFMA/wave/tile.
// LDS: 3 slots x (A 8KB + B 8KB) = 48KB -> 3 blocks/CU.
// Subtile layout (u16): elem(row,k) at (row>>4)*512+((k>>3)&3)*128+(row&15)*8+(k&7)
//   stage chunk c (0..511) -> row=((c>>6)<<4)+(c&15), kk=((c>>4)&3)*8,
//   dest = c*8 (linear, rule #21); frag: rb*512 + ln*8 -> conflict-free b128.
// r9 ledger: compute tile t from slot[t%3], stage t+2 into slot[(t+2)%3]
// (freed by barrier at end of t-1); per tile ONE barrier preceded by counted
// vmcnt(4) (t+1 landed; only t+2's 4 loads may fly). Never vmcnt(0) mid-loop.
// STORE: 0=f32, 1=split bf16, 2=bf16, 3=quant 2-limb i8 (Ch,Cl reinterp).
template <int NSEG, int STORE>
__global__ __launch_bounds__(256, 3) void gemmc(
    const u16* __restrict__ A0, const u16* __restrict__ A1,
    const u16* __restrict__ A2, const u16* __restrict__ B0,
    const u16* __restrict__ B1, const u16* __restrict__ B2,
    float* __restrict__ Cf, u16* __restrict__ Ch, u16* __restrict__ Cl,
    int Kseg, int lda, int ldb, int ldc,
    long long sA, long long sB, long long sC) {
  constexpr int ASZ = 4096;  // 128x32 u16
  constexpr int SLOT = 2 * ASZ;
  __shared__ u16 lds[3 * SLOT];  // 48 KB

  const int tid = threadIdx.x;
  const int ln = tid & 63;
  const int wid = tid >> 6;   // 0..3
  const int wm = wid >> 1;    // 0..1
  const int wn = wid & 1;     // 0..1
  const int m0 = blockIdx.y * 128;
  const int n0 = blockIdx.x * 128;
  const int z = blockIdx.z;
  const long long za = (long long)z * sA;
  const long long zb = (long long)z * sB;

  const int NT = NSEG * (Kseg >> 5);

  f32x4 acc[4][4];
  const f32x4 zero = {0.f, 0.f, 0.f, 0.f};
#pragma unroll
  for (int i = 0; i < 4; i++)
#pragma unroll
    for (int j = 0; j < 4; j++) acc[i][j] = zero;

  auto baseA = [&](int t) -> const u16* {
    int kk = t << 5;
    const u16* p = A0;
    if (NSEG >= 2 && kk >= Kseg) { kk -= Kseg; p = A1; }
    if (NSEG >= 3 && kk >= Kseg) { kk -= Kseg; p = A2; }
    return p + za + (size_t)m0 * lda + kk;
  };
  auto baseB = [&](int t) -> const u16* {
    int kk = t << 5;
    const u16* p = B0;
    if (NSEG >= 2 && kk >= Kseg) { kk -= Kseg; p = B1; }
    if (NSEG >= 3 && kk >= Kseg) { kk -= Kseg; p = B2; }
    return p + zb + (size_t)n0 * ldb + kk;
  };
  auto stage = [&](int t) {
    u16* slot = lds + (t % 3) * SLOT;
    const u16* Ab = baseA(t);
    const u16* Bb = baseB(t);
#pragma unroll
    for (int l = 0; l < 2; ++l) {  // A: 512 chunks
      const int c = tid + l * 256;
      const int row = ((c >> 6) << 4) + (c & 15);
      const int kk = ((c >> 4) & 3) * 8;
      gload_lds16(Ab + (size_t)row * lda + kk, slot + c * 8);
    }
#pragma unroll
    for (int l = 0; l < 2; ++l) {  // B: 512 chunks
      const int c = tid + l * 256;
      const int row = ((c >> 6) << 4) + (c & 15);
      const int kk = ((c >> 4) & 3) * 8;
      gload_lds16(Bb + (size_t)row * ldb + kk, slot + ASZ + c * 8);
    }
  };

  stage(0);
  stage(1);
  wait_vmcnt<4>();
  __builtin_amdgcn_s_barrier();
  __builtin_amdgcn_sched_barrier(0);

  for (int t = 0; t < NT; ++t) {
    if (t + 2 < NT) stage(t + 2);
    const u16* Abuf = lds + (t % 3) * SLOT;
    const u16* Bbuf = Abuf + ASZ;
    const int fo = ln * 8;
    bf16x8 a[4], b[4];
#pragma unroll
    for (int j = 0; j < 4; ++j)
      b[j] = *(const bf16x8*)(Bbuf + (wn * 4 + j) * 512 + fo);
#pragma unroll
    for (int i = 0; i < 4; ++i)
      a[i] = *(const bf16x8*)(Abuf + (wm * 4 + i) * 512 + fo);
    __builtin_amdgcn_s_setprio(1);
#pragma unroll
    for (int i = 0; i < 4; ++i)
#pragma unroll
      for (int j = 0; j < 4; ++j)
        acc[i][j] = __builtin_amdgcn_mfma_f32_16x16x32_bf16(
            a[i], b[j], acc[i][j], 0, 0, 0);
    __builtin_amdgcn_s_setprio(0);
    if (t + 1 < NT) {
      if (t + 2 < NT) wait_vmcnt<4>();
      else            wait_vmcnt<0>();
      __builtin_amdgcn_s_barrier();
      __builtin_amdgcn_sched_barrier(0);
    }
  }

  // epilogue: C/D layout col=lane&15, row=(lane>>4)*4+reg (validated r2-r12)
  const int orow = (ln >> 4) * 4;
  const int ocol = ln & 15;
#pragma unroll
  for (int mi = 0; mi < 4; ++mi)
#pragma unroll
    for (int ni = 0; ni < 4; ++ni) {
      const int rbase = m0 + wm * 64 + mi * 16 + orow;
      const int cc = n0 + wn * 64 + ni * 16 + ocol;
#pragma unroll
      for (int i = 0; i < 4; ++i) {
        const float v = acc[mi][ni][i];
        const long long off =
            (long long)(rbase + i) * ldc + cc + (long long)z * sC;
        if (STORE == 0) {
          Cf[off] = v;
        } else if (STORE == 1) {
          const u16 h = f2bf(v);
          Ch[off] = h;
          Cl[off] = f2bf(v - bf2f(h));
        } else if (STORE == 2) {
          Ch[off] = f2bf(v);
        } else {  // quantize to 2-limb i8 (x ~ a/16 + b/2048)
          const int qa = clamp127(__float2int_rn(v * 16.f));
          const int qb = clamp127(__float2int_rn((v - qa * 0.0625f) * 2048.f));
          ((s8*)Ch)[off] = (s8)qa;
          ((s8*)Cl)[off] = (s8)qb;
        }
      }
    }
}

// ===== i8 GEMM for QKT: NT, BM=BN=128, BK=64; 3 segments
// (Qa.Ka->accA, Qa.Kb->accC, Qb.Ka->accC); logit = accA/256 + accC/32768.
// 256 thr = 4 waves (2x2), wave tile 64x64, 16 MFMA(x64)/wave/tile.
// LDS subtile (bytes): elem(row,k) at (row>>4)*1024+((k>>4)&3)*256+
//   (row&15)*16+(k&15); chunk c (0..511) -> row=((c>>6)<<4)+(c&15),
//   kk=((c>>4)&3)*16, dest=c*16 (linear); frag fo=(ln>>4)*256+(ln&15)*16.
// Same ledger: 3 slots (48KB), lead 2, vmcnt(4). STORE split-bf16 (Lh,Ll).
__global__ __launch_bounds__(256, 2) void gemmq(
    const s8* __restrict__ A0, const s8* __restrict__ A1,
    const s8* __restrict__ A2, const s8* __restrict__ B0,
    const s8* __restrict__ B1, const s8* __restrict__ B2,
    u16* __restrict__ Ch, u16* __restrict__ Cl,
    int Kseg, int lda, int ldb, int ldc,
    long long sA, long long sB, long long sC) {
  constexpr int ASZ = 128 * 64;  // bytes
  constexpr int SLOT = 2 * ASZ;
  __shared__ s8 lds[3 * SLOT];  // 48 KB

  const int tid = threadIdx.x;
  const int ln = tid & 63;
  const int wid = tid >> 6;
  const int wm = wid >> 1;
  const int wn = wid & 1;
  const int m0 = blockIdx.y * 128;
  const int n0 = blockIdx.x * 128;
  const int z = blockIdx.z;
  const long long za = (long long)z * sA;
  const long long zb = (long long)z * sB;

  const int TPS = Kseg >> 6;  // tiles per segment (16 for K=1024)
  const int NT = 3 * TPS;

  i32x4 accA[4][4], accC[4][4];
  const i32x4 izero = {0, 0, 0, 0};
#pragma unroll
  for (int i = 0; i < 4; i++)
#pragma unroll
    for (int j = 0; j < 4; j++) { accA[i][j] = izero; accC[i][j] = izero; }

  auto baseA = [&](int t) -> const s8* {
    int kk = t << 6;
    const s8* p = A0;
    if (kk >= Kseg) { kk -= Kseg; p = A1; }
    if (kk >= Kseg) { kk -= Kseg; p = A2; }
    return p + za + (size_t)m0 * lda + kk;
  };
  auto baseB = [&](int t) -> const s8* {
    int kk = t << 6;
    const s8* p = B0;
    if (kk >= Kseg) { kk -= Kseg; p = B1; }
    if (kk >= Kseg) { kk -= Kseg; p = B2; }
    return p + zb + (size_t)n0 * ldb + kk;
  };
  auto stage = [&](int t) {
    s8* slot = lds + (t % 3) * SLOT;
    const s8* Ab = baseA(t);
    const s8* Bb = baseB(t);
#pragma unroll
    for (int l = 0; l < 2; ++l) {  // A: 512 chunks
      const int c = tid + l * 256;
      const int row = ((c >> 6) << 4) + (c & 15);
      const int kk = ((c >> 4) & 3) * 16;
      gload_lds16(Ab + (size_t)row * lda + kk, slot + c * 16);
    }
#pragma unroll
    for (int l = 0; l < 2; ++l) {  // B: 512 chunks
      const int c = tid + l * 256;
      const int row = ((c >> 6) << 4) + (c & 15);
      const int kk = ((c >> 4) & 3) * 16;
      gload_lds16(Bb + (size_t)row * ldb + kk, slot + ASZ + c * 16);
    }
  };

  stage(0);
  stage(1);
  wait_vmcnt<4>();
  __builtin_amdgcn_s_barrier();
  __builtin_amdgcn_sched_barrier(0);

  for (int t = 0; t < NT; ++t) {
    if (t + 2 < NT) stage(t + 2);
    const s8* Abuf = lds + (t % 3) * SLOT;
    const s8* Bbuf = Abuf + ASZ;
    const int fo = (ln >> 4) * 256 + (ln & 15) * 16;
    i32x4 a[4], b[4];
#pragma unroll
    for (int j = 0; j < 4; ++j)
      b[j] = *(const i32x4*)(Bbuf + (wn * 4 + j) * 1024 + fo);
#pragma unroll
    for (int i = 0; i < 4; ++i)
      a[i] = *(const i32x4*)(Abuf + (wm * 4 + i) * 1024 + fo);
    __builtin_amdgcn_s_setprio(1);
    if (t < TPS) {
#pragma unroll
      for (int i = 0; i < 4; ++i)
#pragma unroll
        for (int j = 0; j < 4; ++j)
          accA[i][j] = __builtin_amdgcn_mfma_i32_16x16x64_i8(
              a[i], b[j], accA[i][j], 0, 0, 0);
    } else {
#pragma unroll
      for (int i = 0; i < 4; ++i)
#pragma unroll
        for (int j = 0; j < 4; ++j)
          accC[i][j] = __builtin_amdgcn_mfma_i32_16x16x64_i8(
              a[i], b[j], accC[i][j], 0, 0, 0);
    }
    __builtin_amdgcn_s_setprio(0);
    if (t + 1 < NT) {
      if (t + 2 < NT) wait_vmcnt<4>();
      else            wait_vmcnt<0>();
      __builtin_amdgcn_s_barrier();
      __builtin_amdgcn_sched_barrier(0);
    }
  }

  const int orow = (ln >> 4) * 4;
  const int ocol = ln & 15;
#pragma unroll
  for (int mi = 0; mi < 4; ++mi)
#pragma unroll
    for (int ni = 0; ni < 4; ++ni) {
      const int rbase = m0 + wm * 64 + mi * 16 + orow;
      const int cc = n0 + wn * 64 + ni * 16 + ocol;
#pragma unroll
      for (int i = 0; i < 4; ++i) {
        const float v = (float)accA[mi][ni][i] * 0.00390625f +
                        (float)accC[mi][ni][i] * 3.0517578125e-05f;
        const long long off =
            (long long)(rbase + i) * ldc + cc + (long long)z * sC;
        const u16 h = f2bf(v);
        Ch[off] = h;
        Cl[off] = f2bf(v - bf2f(h));
      }
    }
}

// ---- softmax (row = 2048) ----
__device__ __forceinline__ float blk_max(float v, float* red) {
  const int wv = threadIdx.x >> 6, lnn = threadIdx.x & 63;
#pragma unroll
  for (int off = 32; off; off >>= 1) v = fmaxf(v, __shfl_xor(v, off));
  if (lnn == 0) red[wv] = v;
  __syncthreads();
  return fmaxf(fmaxf(red[0], red[1]), fmaxf(red[2], red[3]));
}
__device__ __forceinline__ float blk_sum(float v, float* red) {
  const int wv = threadIdx.x >> 6, lnn = threadIdx.x & 63;
#pragma unroll
  for (int off = 32; off; off >>= 1) v += __shfl_xor(v, off);
  if (lnn == 0) red[wv] = v;
  __syncthreads();
  return red[0] + red[1] + red[2] + red[3];
}

// f32 L row -> bf16 P in place (row stride stays 4096 u16) [low tier]
__global__ __launch_bounds__(256) void softmax_inplace(float* __restrict__ L) {
  float* p = L + (size_t)blockIdx.x * 2048;
  const int t = threadIdx.x;
  __shared__ float redm[4];
  __shared__ float reds[4];
  float4 x0 = *(const float4*)(p + t * 4);
  float4 x1 = *(const float4*)(p + 1024 + t * 4);
  float m = fmaxf(fmaxf(fmaxf(x0.x, x0.y), fmaxf(x0.z, x0.w)),
                  fmaxf(fmaxf(x1.x, x1.y), fmaxf(x1.z, x1.w)));
  m = blk_max(m, redm);
  float e[8];
  e[0] = __expf(x0.x - m); e[1] = __expf(x0.y - m);
  e[2] = __expf(x0.z - m); e[3] = __expf(x0.w - m);
  e[4] = __expf(x1.x - m); e[5] = __expf(x1.y - m);
  e[6] = __expf(x1.z - m); e[7] = __expf(x1.w - m);
  float s = e[0] + e[1] + e[2] + e[3] + e[4] + e[5] + e[6] + e[7];
  s = blk_sum(s, reds);
  const float inv = 1.f / s;
  u16* q = (u16*)p;
  ushort4 o0, o1;
  o0.x = f2bf(e[0] * inv); o0.y = f2bf(e[1] * inv);
  o0.z = f2bf(e[2] * inv); o0.w = f2bf(e[3] * inv);
  o1.x = f2bf(e[4] * inv); o1.y = f2bf(e[5] * inv);
  o1.z = f2bf(e[6] * inv); o1.w = f2bf(e[7] * inv);
  *(ushort4*)(q + t * 4) = o0;
  *(ushort4*)(q + 1024 + t * 4) = o1;
}

// split-bf16 L (Lh+Ll) -> bf16 P over Lh row (stride 2048 u16)
__global__ __launch_bounds__(256) void softmax_split(
    u16* __restrict__ Lh, const u16* __restrict__ Ll) {
  u16* ph = Lh + (size_t)blockIdx.x * 2048;
  const u16* pl = Ll + (size_t)blockIdx.x * 2048;
  const int t = threadIdx.x;
  __shared__ float redm[4];
  __shared__ float reds[4];
  ushort4 h0 = *(const ushort4*)(ph + t * 4);
  ushort4 h1 = *(const ushort4*)(ph + 1024 + t * 4);
  ushort4 l0 = *(const ushort4*)(pl + t * 4);
  ushort4 l1 = *(const ushort4*)(pl + 1024 + t * 4);
  float x[8];
  x[0] = bf2f(h0.x) + bf2f(l0.x); x[1] = bf2f(h0.y) + bf2f(l0.y);
  x[2] = bf2f(h0.z) + bf2f(l0.z); x[3] = bf2f(h0.w) + bf2f(l0.w);
  x[4] = bf2f(h1.x) + bf2f(l1.x); x[5] = bf2f(h1.y) + bf2f(l1.y);
  x[6] = bf2f(h1.z) + bf2f(l1.z); x[7] = bf2f(h1.w) + bf2f(l1.w);
  float m = fmaxf(fmaxf(fmaxf(x[0], x[1]), fmaxf(x[2], x[3])),
                  fmaxf(fmaxf(x[4], x[5]), fmaxf(x[6], x[7])));
  m = blk_max(m, redm);
  float e[8];
#pragma unroll
  for (int j = 0; j < 8; ++j) e[j] = __expf(x[j] - m);
  float s = e[0] + e[1] + e[2] + e[3] + e[4] + e[5] + e[6] + e[7];
  s = blk_sum(s, reds);
  const float inv = 1.f / s;
  ushort4 o0, o1;
  o0.x = f2bf(e[0] * inv); o0.y = f2bf(e[1] * inv);
  o0.z = f2bf(e[2] * inv); o0.w = f2bf(e[3] * inv);
  o1.x = f2bf(e[4] * inv); o1.y = f2bf(e[5] * inv);
  o1.z = f2bf(e[6] * inv); o1.w = f2bf(e[7] * inv);
  *(ushort4*)(ph + t * 4) = o0;
  *(ushort4*)(ph + 1024 + t * 4) = o1;
}

extern "C" void kernel_launch(void* const* d_in, const int* in_sizes, int n_in,
                              void* d_out, int out_size, void* d_ws, size_t ws_size,
                              hipStream_t stream) {
  constexpr int Bn = 4, S = 2048, D = 1024;
  constexpr long long TOK = (long long)Bn * S;  // 8192
  constexpr long long DD = (long long)D * D;
  const float* X = (const float*)d_in[0];
  const float* Wq = (const float*)d_in[1];
  const float* Wk = (const float*)d_in[2];
  const float* Wv = (const float*)d_in[3];
  float* out = (float*)d_out;
  const dim3 blk(256);

  char* w = (char*)d_ws;
  auto au16 = [&](long long n) { u16* p = (u16*)w; w += n * 2; return p; };
  auto as8 = [&](long long n) { s8* p = (s8*)w; w += n; return p; };

  if (ws_size >= (size_t)127926272ULL) {
    // Layout (127.93 MB): Xh Xl | Wch Wcl Wvh | QKa QKb (i8) | VT | Ll
    u16* Xh = au16(TOK * D);          // dead after VT -> hosts Lh
    u16* Xl = au16(TOK * D);
    u16* Wch = au16(2 * DD);
    u16* Wcl = au16(2 * DD);
    u16* Wvh = au16(DD);
    s8* QKa = as8(TOK * 2 * D);       // i8 hi plane, cols 0..1023=Q, rest=K
    s8* QKb = as8(TOK * 2 * D);       // i8 lo plane
    u16* VT = au16((long long)D * TOK);  // [1024][8192]
    u16* Ll = au16(TOK * S);          // logit lo plane (tail)
    u16* Lh = (u16*)d_ws;             // logit hi plane over dead X region

    split_f32_kernel<true><<<2048, blk, 0, stream>>>(X, Xh, Xl, TOK * D);
    split_f32_kernel<true><<<512, blk, 0, stream>>>(Wq, Wch, Wcl, DD);
    split_f32_kernel<true><<<512, blk, 0, stream>>>(Wk, Wch + DD, Wcl + DD, DD);
    split_f32_kernel<false><<<512, blk, 0, stream>>>(Wv, Wvh, nullptr, DD);

    // fused Q|K projection (split-bf16 3-seg) -> i8 planes: (16,64) = 1024
    gemmc<3, 3><<<dim3(16, 64, 1), blk, 0, stream>>>(
        Xh, Xh, Xl, Wch, Wcl, Wch, nullptr, (u16*)QKa, (u16*)QKb,
        D, D, D, 2 * D, 0, 0, 0);
    // VT[e,tok] = Wvh . Xh^T : (64,8) = 512 blocks
    gemmc<1, 2><<<dim3(64, 8, 1), blk, 0, stream>>>(
        Wvh, nullptr, nullptr, Xh, nullptr, nullptr, nullptr, VT, nullptr,
        D, D, D, (int)TOK, 0, 0, 0);
    // X region dead now.

    // QKT i8 2-limb, one z=4 launch: (16,16,4) = 1024 blocks
    gemmq<<<dim3(16, 16, 4), blk, 0, stream>>>(
        QKa, QKa, QKb, QKa + D, QKb + D, QKa + D,
        Lh, Ll, D, 2 * D, 2 * D, S,
        (long long)S * 2 * D, (long long)S * 2 * D, (long long)S * S);
    softmax_split<<<dim3(4 * S), blk, 0, stream>>>(Lh, Ll);
    // O = P . VT^T : (8,16,4) = 512 blocks
    gemmc<1, 0><<<dim3(8, 16, 4), blk, 0, stream>>>(
        Lh, nullptr, nullptr, VT, nullptr, nullptr,
        out, nullptr, nullptr, S, S, (int)TOK, D,
        (long long)S * S, (long long)S, (long long)S * D);
  } else {
    // Low tier (~82 MB): per-batch bf16 path
    u16* Xh = au16(TOK * D);
    u16* Xl = au16(TOK * D);
    u16* Wch = au16(2 * DD);
    u16* Wcl = au16(2 * DD);
    u16* Wvh = au16(DD);
    u16* QKhb = au16((long long)S * 2 * D);
    u16* QKlb = au16((long long)S * 2 * D);
    u16* VTb = au16((long long)D * S);
    float* Lb = (float*)w;

    split_f32_kernel<true><<<2048, blk, 0, stream>>>(X, Xh, Xl, TOK * D);
    split_f32_kernel<true><<<512, blk, 0, stream>>>(Wq, Wch, Wcl, DD);
    split_f32_kernel<true><<<512, blk, 0, stream>>>(Wk, Wch + DD, Wcl + DD, DD);
    split_f32_kernel<false><<<512, blk, 0, stream>>>(Wv, Wvh, nullptr, DD);

    for (int b = 0; b < Bn; ++b) {
      const long long xo = (long long)b * S * D;
      gemmc<3, 1><<<dim3(16, 16, 1), blk, 0, stream>>>(
          Xh + xo, Xh + xo, Xl + xo, Wch, Wcl, Wch, nullptr, QKhb, QKlb,
          D, D, D, 2 * D, 0, 0, 0);
      gemmc<1, 2><<<dim3(16, 8, 1), blk, 0, stream>>>(
          Wvh, nullptr, nullptr, Xh + xo, nullptr, nullptr, nullptr, VTb,
          nullptr, D, D, D, S, 0, 0, 0);
      gemmc<3, 0><<<dim3(16, 16, 1), blk, 0, stream>>>(
          QKhb, QKhb, QKlb, QKhb + D, QKlb + D, QKhb + D,
          Lb, nullptr, nullptr, D, 2 * D, 2 * D, S, 0, 0, 0);
      softmax_inplace<<<dim3(S), blk, 0, stream>>>(Lb);
      gemmc<1, 0><<<dim3(8, 16, 1), blk, 0, stream>>>(
          (const u16*)Lb, nullptr, nullptr, VTb, nullptr, nullptr,
          out + xo, nullptr, nullptr, S, 2 * S, S, D, 0, 0, 0);
    }
  }
}

// Round 14
// 384.952 us; speedup vs baseline: 1.7739x; 1.7739x over previous
//
#include <hip/hip_runtime.h>
#include <math.h>

// SelfAttention B=4,S=2048,D=1024 fp32. Round 14: r11 (478us champion) with
// ONE change: fused-split projection kernel gemmf. Stages Xh/Xl/Wh/Wl once
// per BK=32 tile (4 planes, 64KB slot, 2 slots) and computes hh+hl+lh into
// the same accumulators -> 33% fewer staged bytes than concat-K (3 segs).
// Everything else verbatim r11: gemmc (bf16, 3-slot lead-2 counted vmcnt),
// gemmq (2-limb i8 QKT, BK=64), softmax_split, tier layout.

typedef unsigned short u16;
typedef signed char s8;
typedef __attribute__((ext_vector_type(8))) short bf16x8;
typedef __attribute__((ext_vector_type(4))) float f32x4;
typedef __attribute__((ext_vector_type(4))) int i32x4;

__device__ __forceinline__ u16 f2bf(float x) {
  unsigned u = __float_as_uint(x);
  unsigned r = (u + 0x7fffu + ((u >> 16) & 1u)) >> 16;
  return (u16)r;
}
__device__ __forceinline__ float bf2f(u16 h) {
  return __uint_as_float((unsigned)h << 16);
}
__device__ __forceinline__ int clamp127(int q) {
  return q < -127 ? -127 : (q > 127 ? 127 : q);
}

__device__ __forceinline__ void gload_lds16(const void* g, void* l) {
  __builtin_amdgcn_global_load_lds(
      (const __attribute__((address_space(1))) unsigned int*)(g),
      (__attribute__((address_space(3))) unsigned int*)(l), 16, 0, 0);
}

template <int N>
__device__ __forceinline__ void wait_vmcnt() {
  if constexpr (N == 0) asm volatile("s_waitcnt vmcnt(0)" ::: "memory");
  else if constexpr (N == 3) asm volatile("s_waitcnt vmcnt(3)" ::: "memory");
  else if constexpr (N == 4) asm volatile("s_waitcnt vmcnt(4)" ::: "memory");
  else if constexpr (N == 6) asm volatile("s_waitcnt vmcnt(6)" ::: "memory");
}

// fp32 -> hi bf16 (+ optional lo bf16), grid-stride, vectorized
template <bool LO>
__global__ __launch_bounds__(256) void split_f32_kernel(
    const float* __restrict__ in, u16* __restrict__ hi, u16* __restrict__ lo,
    long long n) {
  long long i = ((long long)blockIdx.x * 256 + threadIdx.x) * 4;
  const long long step = (long long)gridDim.x * 256 * 4;
  for (; i < n; i += step) {
    float4 x = *(const float4*)(in + i);
    float xs[4] = {x.x, x.y, x.z, x.w};
    u16 hv[4], lv[4];
#pragma unroll
    for (int j = 0; j < 4; j++) {
      hv[j] = f2bf(xs[j]);
      if (LO) lv[j] = f2bf(xs[j] - bf2f(hv[j]));
    }
    ushort4 h;
    h.x = hv[0]; h.y = hv[1]; h.z = hv[2]; h.w = hv[3];
    *(ushort4*)(hi + i) = h;
    if (LO) {
      ushort4 l;
      l.x = lv[0]; l.y = lv[1]; l.z = lv[2]; l.w = lv[3];
      *(ushort4*)(lo + i) = l;
    }
  }
}

// ===== fused-split projection: [Q|K](8192x2048) i8 2-limb planes from
// (Xh+Xl) @ (Wh+Wl)^T via hh+hl+lh. BM=BN=256, BK=32, 512 thr = 8 waves
// (2M x 4N), wave tile 128x64 (acc[8][4]). LDS: 2 slots x 4 planes x 16KB
// = 128KB. Ledger: lead-1; stage(t+1) issued at tile-t start; per-tile
// compute = 96 MFMA/wave (~960 cyc/SIMD) covers load latency; end-of-tile
// vmcnt(0)+barrier. WAR: slot (t+1)&1 last read in tile t-1, separated by
// that tile's end barrier. Subtile layout per plane (u16, validated):
//   elem(row,k) at (row>>4)*512+((k>>3)&3)*128+(row&15)*8+(k&7)
//   chunk c -> row=((c>>6)<<4)+(c&15), kk=((c>>4)&3)*8, dest=c*8 (linear).
__global__ __launch_bounds__(512, 2) void gemmf(
    const u16* __restrict__ Xh, const u16* __restrict__ Xl,
    const u16* __restrict__ Wh, const u16* __restrict__ Wl,
    s8* __restrict__ Ca, s8* __restrict__ Cb) {
  constexpr int PL = 8192;         // u16 per 256x32 plane
  __shared__ u16 lds[2 * 4 * PL];  // 128 KB

  const int tid = threadIdx.x;
  const int ln = tid & 63;
  const int wid = tid >> 6;
  const int wm = wid >> 2;  // 0..1
  const int wn = wid & 3;   // 0..3
  const int m0 = blockIdx.y * 256;
  const int n0 = blockIdx.x * 256;

  f32x4 acc[8][4];
  const f32x4 zero = {0.f, 0.f, 0.f, 0.f};
#pragma unroll
  for (int i = 0; i < 8; i++)
#pragma unroll
    for (int j = 0; j < 4; j++) acc[i][j] = zero;

  auto stage = [&](int t) {
    u16* slot = lds + (t & 1) * 4 * PL;
    const int k0 = t << 5;
#pragma unroll
    for (int l = 0; l < 2; ++l) {
      const int c = tid + l * 512;
      const int row = ((c >> 6) << 4) + (c & 15);
      const int kk = ((c >> 4) & 3) * 8;
      gload_lds16(Xh + (size_t)(m0 + row) * 1024 + k0 + kk, slot + c * 8);
      gload_lds16(Xl + (size_t)(m0 + row) * 1024 + k0 + kk,
                  slot + PL + c * 8);
      gload_lds16(Wh + (size_t)(n0 + row) * 1024 + k0 + kk,
                  slot + 2 * PL + c * 8);
      gload_lds16(Wl + (size_t)(n0 + row) * 1024 + k0 + kk,
                  slot + 3 * PL + c * 8);
    }
  };

  stage(0);
  wait_vmcnt<0>();
  __builtin_amdgcn_s_barrier();
  __builtin_amdgcn_sched_barrier(0);

  for (int t = 0; t < 32; ++t) {
    if (t + 1 < 32) stage(t + 1);
    const u16* Ah = lds + (t & 1) * 4 * PL;
    const u16* Al = Ah + PL;
    const u16* Bh = Ah + 2 * PL;
    const u16* Bl = Ah + 3 * PL;
    const int fo = ln * 8;
    bf16x8 bh[4], bl[4];
#pragma unroll
    for (int j = 0; j < 4; ++j) {
      bh[j] = *(const bf16x8*)(Bh + (wn * 4 + j) * 512 + fo);
      bl[j] = *(const bf16x8*)(Bl + (wn * 4 + j) * 512 + fo);
    }
    __builtin_amdgcn_s_setprio(1);
#pragma unroll
    for (int mh = 0; mh < 2; ++mh) {
      bf16x8 ah[4], al[4];
#pragma unroll
      for (int i = 0; i < 4; ++i) {
        ah[i] = *(const bf16x8*)(Ah + (wm * 8 + mh * 4 + i) * 512 + fo);
        al[i] = *(const bf16x8*)(Al + (wm * 8 + mh * 4 + i) * 512 + fo);
      }
#pragma unroll
      for (int i = 0; i < 4; ++i)
#pragma unroll
        for (int j = 0; j < 4; ++j) {
          f32x4 v = acc[mh * 4 + i][j];
          v = __builtin_amdgcn_mfma_f32_16x16x32_bf16(ah[i], bh[j], v, 0, 0, 0);
          v = __builtin_amdgcn_mfma_f32_16x16x32_bf16(ah[i], bl[j], v, 0, 0, 0);
          v = __builtin_amdgcn_mfma_f32_16x16x32_bf16(al[i], bh[j], v, 0, 0, 0);
          acc[mh * 4 + i][j] = v;
        }
    }
    __builtin_amdgcn_s_setprio(0);
    if (t + 1 < 32) {
      wait_vmcnt<0>();  // tile t+1 landed (issued ~full tile ago)
      __builtin_amdgcn_s_barrier();
      __builtin_amdgcn_sched_barrier(0);
    }
  }

  // epilogue: C/D layout col=lane&15, row=(lane>>4)*4+reg; quant 2-limb i8
  const int orow = (ln >> 4) * 4;
  const int ocol = ln & 15;
#pragma unroll
  for (int mi = 0; mi < 8; ++mi)
#pragma unroll
    for (int ni = 0; ni < 4; ++ni) {
      const int rbase = m0 + wm * 128 + mi * 16 + orow;
      const int cc = n0 + wn * 64 + ni * 16 + ocol;
#pragma unroll
      for (int i = 0; i < 4; ++i) {
        const float v = acc[mi][ni][i];
        const long long off = (long long)(rbase + i) * 2048 + cc;
        const int qa = clamp127(__float2int_rn(v * 16.f));
        const int qb = clamp127(__float2int_rn((v - qa * 0.0625f) * 2048.f));
        Ca[off] = (s8)qa;
        Cb[off] = (s8)qb;
      }
    }
}

// ===== bf16 GEMM (r9/r11-proven): NT over NSEG segs, BK=32, 3 slots,
// lead 2, counted vmcnt(L). BM=32*M_REP, BN=256, 512 thr = 8 waves.
// STORE: 0=f32, 1=split bf16, 2=bf16, 3=quant 2-limb i8.
template <int NSEG, int STORE, int M_REP>
__global__ __launch_bounds__(512, 2) void gemmc(
    const u16* __restrict__ A0, const u16* __restrict__ A1,
    const u16* __restrict__ A2, const u16* __restrict__ B0,
    const u16* __restrict__ B1, const u16* __restrict__ B2,
    float* __restrict__ Cf, u16* __restrict__ Ch, u16* __restrict__ Cl,
    int Kseg, int lda, int ldb, int ldc,
    long long sA, long long sB, long long sC) {
  constexpr int BM = 32 * M_REP;
  constexpr int ASZ = BM * 32;   // u16
  constexpr int BSZ = 8192;      // 256x32 u16
  constexpr int SLOT = ASZ + BSZ;
  constexpr int LA = M_REP / 4;
  constexpr int L = LA + 2;
  __shared__ u16 lds[3 * SLOT];

  const int tid = threadIdx.x;
  const int ln = tid & 63;
  const int wid = tid >> 6;
  const int wm = wid >> 2;
  const int wn = wid & 3;
  const int m0 = blockIdx.y * BM;
  const int n0 = blockIdx.x * 256;
  const int z = blockIdx.z;
  const long long za = (long long)z * sA;
  const long long zb = (long long)z * sB;

  const int NT = NSEG * (Kseg >> 5);

  f32x4 acc[M_REP][4];
  const f32x4 zero = {0.f, 0.f, 0.f, 0.f};
#pragma unroll
  for (int i = 0; i < M_REP; i++)
#pragma unroll
    for (int j = 0; j < 4; j++) acc[i][j] = zero;

  auto baseA = [&](int t) -> const u16* {
    int kk = t << 5;
    const u16* p = A0;
    if (NSEG >= 2 && kk >= Kseg) { kk -= Kseg; p = A1; }
    if (NSEG >= 3 && kk >= Kseg) { kk -= Kseg; p = A2; }
    return p + za + (size_t)m0 * lda + kk;
  };
  auto baseB = [&](int t) -> const u16* {
    int kk = t << 5;
    const u16* p = B0;
    if (NSEG >= 2 && kk >= Kseg) { kk -= Kseg; p = B1; }
    if (NSEG >= 3 && kk >= Kseg) { kk -= Kseg; p = B2; }
    return p + zb + (size_t)n0 * ldb + kk;
  };
  auto stage = [&](int t) {
    u16* slot = lds + (t % 3) * SLOT;
    const u16* Ab = baseA(t);
    const u16* Bb = baseB(t);
#pragma unroll
    for (int l = 0; l < LA; ++l) {
      const int c = tid + l * 512;
      const int row = ((c >> 6) << 4) + (c & 15);
      const int kk = ((c >> 4) & 3) * 8;
      gload_lds16(Ab + (size_t)row * lda + kk, slot + c * 8);
    }
#pragma unroll
    for (int l = 0; l < 2; ++l) {
      const int c = tid + l * 512;
      const int row = ((c >> 6) << 4) + (c & 15);
      const int kk = ((c >> 4) & 3) * 8;
      gload_lds16(Bb + (size_t)row * ldb + kk, slot + ASZ + c * 8);
    }
  };

  stage(0);
  stage(1);
  wait_vmcnt<L>();
  __builtin_amdgcn_s_barrier();
  __builtin_amdgcn_sched_barrier(0);

  for (int t = 0; t < NT; ++t) {
    if (t + 2 < NT) stage(t + 2);
    const u16* Abuf = lds + (t % 3) * SLOT;
    const u16* Bbuf = Abuf + ASZ;
    const int fo = ln * 8;
    bf16x8 a[M_REP], b[4];
#pragma unroll
    for (int j = 0; j < 4; ++j)
      b[j] = *(const bf16x8*)(Bbuf + (wn * 4 + j) * 512 + fo);
#pragma unroll
    for (int i = 0; i < M_REP; ++i)
      a[i] = *(const bf16x8*)(Abuf + (wm * M_REP + i) * 512 + fo);
    __builtin_amdgcn_s_setprio(1);
#pragma unroll
    for (int i = 0; i < M_REP; ++i)
#pragma unroll
      for (int j = 0; j < 4; ++j)
        acc[i][j] = __builtin_amdgcn_mfma_f32_16x16x32_bf16(
            a[i], b[j], acc[i][j], 0, 0, 0);
    __builtin_amdgcn_s_setprio(0);
    if (t + 1 < NT) {
      if (t + 2 < NT) wait_vmcnt<L>();
      else            wait_vmcnt<0>();
      __builtin_amdgcn_s_barrier();
      __builtin_amdgcn_sched_barrier(0);
    }
  }

  const int orow = (ln >> 4) * 4;
  const int ocol = ln & 15;
#pragma unroll
  for (int mi = 0; mi < M_REP; ++mi)
#pragma unroll
    for (int ni = 0; ni < 4; ++ni) {
      const int rbase = m0 + wm * (M_REP * 16) + mi * 16 + orow;
      const int cc = n0 + wn * 64 + ni * 16 + ocol;
#pragma unroll
      for (int i = 0; i < 4; ++i) {
        const float v = acc[mi][ni][i];
        const long long off =
            (long long)(rbase + i) * ldc + cc + (long long)z * sC;
        if (STORE == 0) {
          Cf[off] = v;
        } else if (STORE == 1) {
          const u16 h = f2bf(v);
          Ch[off] = h;
          Cl[off] = f2bf(v - bf2f(h));
        } else if (STORE == 2) {
          Ch[off] = f2bf(v);
        } else {
          const int qa = clamp127(__float2int_rn(v * 16.f));
          const int qb = clamp127(__float2int_rn((v - qa * 0.0625f) * 2048.f));
          ((s8*)Ch)[off] = (s8)qa;
          ((s8*)Cl)[off] = (s8)qb;
        }
      }
    }
}

// ===== i8 GEMM for QKT (r11-proven): NT, BK=64, BM=128, BN=256; 3 segments
// (Qa.Ka->accA, Qa.Kb->accC, Qb.Ka->accC); logit = accA/256 + accC/32768.
__global__ __launch_bounds__(512, 2) void gemmq(
    const s8* __restrict__ A0, const s8* __restrict__ A1,
    const s8* __restrict__ A2, const s8* __restrict__ B0,
    const s8* __restrict__ B1, const s8* __restrict__ B2,
    u16* __restrict__ Ch, u16* __restrict__ Cl,
    int Kseg, int lda, int ldb, int ldc,
    long long sA, long long sB, long long sC) {
  constexpr int ASZ = 128 * 64;  // bytes
  constexpr int BSZ = 256 * 64;  // bytes
  constexpr int SLOT = ASZ + BSZ;
  __shared__ s8 lds[3 * SLOT];

  const int tid = threadIdx.x;
  const int ln = tid & 63;
  const int wid = tid >> 6;
  const int wm = wid >> 2;
  const int wn = wid & 3;
  const int m0 = blockIdx.y * 128;
  const int n0 = blockIdx.x * 256;
  const int z = blockIdx.z;
  const long long za = (long long)z * sA;
  const long long zb = (long long)z * sB;

  const int TPS = Kseg >> 6;
  const int NT = 3 * TPS;

  i32x4 accA[4][4], accC[4][4];
  const i32x4 izero = {0, 0, 0, 0};
#pragma unroll
  for (int i = 0; i < 4; i++)
#pragma unroll
    for (int j = 0; j < 4; j++) { accA[i][j] = izero; accC[i][j] = izero; }

  auto baseA = [&](int t) -> const s8* {
    int kk = t << 6;
    const s8* p = A0;
    if (kk >= Kseg) { kk -= Kseg; p = A1; }
    if (kk >= Kseg) { kk -= Kseg; p = A2; }
    return p + za + (size_t)m0 * lda + kk;
  };
  auto baseB = [&](int t) -> const s8* {
    int kk = t << 6;
    const s8* p = B0;
    if (kk >= Kseg) { kk -= Kseg; p = B1; }
    if (kk >= Kseg) { kk -= Kseg; p = B2; }
    return p + zb + (size_t)n0 * ldb + kk;
  };
  auto stage = [&](int t) {
    s8* slot = lds + (t % 3) * SLOT;
    const s8* Ab = baseA(t);
    const s8* Bb = baseB(t);
    {
      const int c = tid;
      const int row = ((c >> 6) << 4) + (c & 15);
      const int kk = ((c >> 4) & 3) * 16;
      gload_lds16(Ab + (size_t)row * lda + kk, slot + c * 16);
    }
#pragma unroll
    for (int l = 0; l < 2; ++l) {
      const int c = tid + l * 512;
      const int row = ((c >> 6) << 4) + (c & 15);
      const int kk = ((c >> 4) & 3) * 16;
      gload_lds16(Bb + (size_t)row * ldb + kk, slot + ASZ + c * 16);
    }
  };

  stage(0);
  stage(1);
  wait_vmcnt<3>();
  __builtin_amdgcn_s_barrier();
  __builtin_amdgcn_sched_barrier(0);

  for (int t = 0; t < NT; ++t) {
    if (t + 2 < NT) stage(t + 2);
    const s8* Abuf = lds + (t % 3) * SLOT;
    const s8* Bbuf = Abuf + ASZ;
    const int fo = (ln >> 4) * 256 + (ln & 15) * 16;
    i32x4 a[4], b[4];
#pragma unroll
    for (int j = 0; j < 4; ++j)
      b[j] = *(const i32x4*)(Bbuf + (wn * 4 + j) * 1024 + fo);
#pragma unroll
    for (int i = 0; i < 4; ++i)
      a[i] = *(const i32x4*)(Abuf + (wm * 4 + i) * 1024 + fo);
    __builtin_amdgcn_s_setprio(1);
    if (t < TPS) {
#pragma unroll
      for (int i = 0; i < 4; ++i)
#pragma unroll
        for (int j = 0; j < 4; ++j)
          accA[i][j] = __builtin_amdgcn_mfma_i32_16x16x64_i8(
              a[i], b[j], accA[i][j], 0, 0, 0);
    } else {
#pragma unroll
      for (int i = 0; i < 4; ++i)
#pragma unroll
        for (int j = 0; j < 4; ++j)
          accC[i][j] = __builtin_amdgcn_mfma_i32_16x16x64_i8(
              a[i], b[j], accC[i][j], 0, 0, 0);
    }
    __builtin_amdgcn_s_setprio(0);
    if (t + 1 < NT) {
      if (t + 2 < NT) wait_vmcnt<3>();
      else            wait_vmcnt<0>();
      __builtin_amdgcn_s_barrier();
      __builtin_amdgcn_sched_barrier(0);
    }
  }

  const int orow = (ln >> 4) * 4;
  const int ocol = ln & 15;
#pragma unroll
  for (int mi = 0; mi < 4; ++mi)
#pragma unroll
    for (int ni = 0; ni < 4; ++ni) {
      const int rbase = m0 + wm * 64 + mi * 16 + orow;
      const int cc = n0 + wn * 64 + ni * 16 + ocol;
#pragma unroll
      for (int i = 0; i < 4; ++i) {
        const float v = (float)accA[mi][ni][i] * 0.00390625f +
                        (float)accC[mi][ni][i] * 3.0517578125e-05f;
        const long long off =
            (long long)(rbase + i) * ldc + cc + (long long)z * sC;
        const u16 h = f2bf(v);
        Ch[off] = h;
        Cl[off] = f2bf(v - bf2f(h));
      }
    }
}

// ---- softmax (row = 2048) ----
__device__ __forceinline__ float blk_max(float v, float* red) {
  const int wv = threadIdx.x >> 6, lnn = threadIdx.x & 63;
#pragma unroll
  for (int off = 32; off; off >>= 1) v = fmaxf(v, __shfl_xor(v, off));
  if (lnn == 0) red[wv] = v;
  __syncthreads();
  return fmaxf(fmaxf(red[0], red[1]), fmaxf(red[2], red[3]));
}
__device__ __forceinline__ float blk_sum(float v, float* red) {
  const int wv = threadIdx.x >> 6, lnn = threadIdx.x & 63;
#pragma unroll
  for (int off = 32; off; off >>= 1) v += __shfl_xor(v, off);
  if (lnn == 0) red[wv] = v;
  __syncthreads();
  return red[0] + red[1] + red[2] + red[3];
}

// f32 L row -> bf16 P in place (row stride stays 4096 u16) [low tier]
__global__ __launch_bounds__(256) void softmax_inplace(float* __restrict__ L) {
  float* p = L + (size_t)blockIdx.x * 2048;
  const int t = threadIdx.x;
  __shared__ float redm[4];
  __shared__ float reds[4];
  float4 x0 = *(const float4*)(p + t * 4);
  float4 x1 = *(const float4*)(p + 1024 + t * 4);
  float m = fmaxf(fmaxf(fmaxf(x0.x, x0.y), fmaxf(x0.z, x0.w)),
                  fmaxf(fmaxf(x1.x, x1.y), fmaxf(x1.z, x1.w)));
  m = blk_max(m, redm);
  float e[8];
  e[0] = __expf(x0.x - m); e[1] = __expf(x0.y - m);
  e[2] = __expf(x0.z - m); e[3] = __expf(x0.w - m);
  e[4] = __expf(x1.x - m); e[5] = __expf(x1.y - m);
  e[6] = __expf(x1.z - m); e[7] = __expf(x1.w - m);
  float s = e[0] + e[1] + e[2] + e[3] + e[4] + e[5] + e[6] + e[7];
  s = blk_sum(s, reds);
  const float inv = 1.f / s;
  u16* q = (u16*)p;
  ushort4 o0, o1;
  o0.x = f2bf(e[0] * inv); o0.y = f2bf(e[1] * inv);
  o0.z = f2bf(e[2] * inv); o0.w = f2bf(e[3] * inv);
  o1.x = f2bf(e[4] * inv); o1.y = f2bf(e[5] * inv);
  o1.z = f2bf(e[6] * inv); o1.w = f2bf(e[7] * inv);
  *(ushort4*)(q + t * 4) = o0;
  *(ushort4*)(q + 1024 + t * 4) = o1;
}

// split-bf16 L (Lh+Ll) -> bf16 P over Lh row (stride 2048 u16)
__global__ __launch_bounds__(256) void softmax_split(
    u16* __restrict__ Lh, const u16* __restrict__ Ll) {
  u16* ph = Lh + (size_t)blockIdx.x * 2048;
  const u16* pl = Ll + (size_t)blockIdx.x * 2048;
  const int t = threadIdx.x;
  __shared__ float redm[4];
  __shared__ float reds[4];
  ushort4 h0 = *(const ushort4*)(ph + t * 4);
  ushort4 h1 = *(const ushort4*)(ph + 1024 + t * 4);
  ushort4 l0 = *(const ushort4*)(pl + t * 4);
  ushort4 l1 = *(const ushort4*)(pl + 1024 + t * 4);
  float x[8];
  x[0] = bf2f(h0.x) + bf2f(l0.x); x[1] = bf2f(h0.y) + bf2f(l0.y);
  x[2] = bf2f(h0.z) + bf2f(l0.z); x[3] = bf2f(h0.w) + bf2f(l0.w);
  x[4] = bf2f(h1.x) + bf2f(l1.x); x[5] = bf2f(h1.y) + bf2f(l1.y);
  x[6] = bf2f(h1.z) + bf2f(l1.z); x[7] = bf2f(h1.w) + bf2f(l1.w);
  float m = fmaxf(fmaxf(fmaxf(x[0], x[1]), fmaxf(x[2], x[3])),
                  fmaxf(fmaxf(x[4], x[5]), fmaxf(x[6], x[7])));
  m = blk_max(m, redm);
  float e[8];
#pragma unroll
  for (int j = 0; j < 8; ++j) e[j] = __expf(x[j] - m);
  float s = e[0] + e[1] + e[2] + e[3] + e[4] + e[5] + e[6] + e[7];
  s = blk_sum(s, reds);
  const float inv = 1.f / s;
  ushort4 o0, o1;
  o0.x = f2bf(e[0] * inv); o0.y = f2bf(e[1] * inv);
  o0.z = f2bf(e[2] * inv); o0.w = f2bf(e[3] * inv);
  o1.x = f2bf(e[4] * inv); o1.y = f2bf(e[5] * inv);
  o1.z = f2bf(e[6] * inv); o1.w = f2bf(e[7] * inv);
  *(ushort4*)(ph + t * 4) = o0;
  *(ushort4*)(ph + 1024 + t * 4) = o1;
}

extern "C" void kernel_launch(void* const* d_in, const int* in_sizes, int n_in,
                              void* d_out, int out_size, void* d_ws, size_t ws_size,
                              hipStream_t stream) {
  constexpr int Bn = 4, S = 2048, D = 1024;
  constexpr long long TOK = (long long)Bn * S;  // 8192
  constexpr long long DD = (long long)D * D;
  const float* X = (const float*)d_in[0];
  const float* Wq = (const float*)d_in[1];
  const float* Wk = (const float*)d_in[2];
  const float* Wv = (const float*)d_in[3];
  float* out = (float*)d_out;
  const dim3 blk(256);
  const dim3 gblk(512);

  char* w = (char*)d_ws;
  auto au16 = [&](long long n) { u16* p = (u16*)w; w += n * 2; return p; };
  auto as8 = [&](long long n) { s8* p = (s8*)w; w += n; return p; };

  if (ws_size >= (size_t)127926272ULL) {
    // Layout (127.93 MB): Xh Xl | Wch Wcl Wvh | QKa QKb (i8) | VT | Ll
    u16* Xh = au16(TOK * D);          // dead after VT -> hosts Lh
    u16* Xl = au16(TOK * D);
    u16* Wch = au16(2 * DD);
    u16* Wcl = au16(2 * DD);
    u16* Wvh = au16(DD);
    s8* QKa = as8(TOK * 2 * D);       // i8 hi plane, cols 0..1023=Q, rest=K
    s8* QKb = as8(TOK * 2 * D);       // i8 lo plane
    u16* VT = au16((long long)D * TOK);  // [1024][8192]
    u16* Ll = au16(TOK * S);          // logit lo plane (tail)
    u16* Lh = (u16*)d_ws;             // logit hi plane over dead X region

    split_f32_kernel<true><<<2048, blk, 0, stream>>>(X, Xh, Xl, TOK * D);
    split_f32_kernel<true><<<512, blk, 0, stream>>>(Wq, Wch, Wcl, DD);
    split_f32_kernel<true><<<512, blk, 0, stream>>>(Wk, Wch + DD, Wcl + DD, DD);
    split_f32_kernel<false><<<512, blk, 0, stream>>>(Wv, Wvh, nullptr, DD);

    // fused-split Q|K projection -> i8 planes: (8,32) = 256 blocks
    gemmf<<<dim3(8, 32, 1), gblk, 0, stream>>>(
        Xh, Xl, Wch, Wcl, QKa, QKb);
    // VT[e,tok] = Wvh . Xh^T : (32,8) = 256 blocks
    gemmc<1, 2, 4><<<dim3(32, 8, 1), gblk, 0, stream>>>(
        Wvh, nullptr, nullptr, Xh, nullptr, nullptr, nullptr, VT, nullptr,
        D, D, D, (int)TOK, 0, 0, 0);
    // X region dead now.

    // QKT i8 2-limb, one z=4 launch: (8,16,4) = 512 blocks
    gemmq<<<dim3(8, 16, 4), gblk, 0, stream>>>(
        QKa, QKa, QKb, QKa + D, QKb + D, QKa + D,
        Lh, Ll, D, 2 * D, 2 * D, S,
        (long long)S * 2 * D, (long long)S * 2 * D, (long long)S * S);
    softmax_split<<<dim3(4 * S), blk, 0, stream>>>(Lh, Ll);
    // O = P . VT^T : (4,16,4) = 256 blocks
    gemmc<1, 0, 4><<<dim3(4, 16, 4), gblk, 0, stream>>>(
        Lh, nullptr, nullptr, VT, nullptr, nullptr,
        out, nullptr, nullptr, S, S, (int)TOK, D,
        (long long)S * S, (long long)S, (long long)S * D);
  } else {
    // Low tier (~82 MB): per-batch bf16 path (r9/r11)
    u16* Xh = au16(TOK * D);
    u16* Xl = au16(TOK * D);
    u16* Wch = au16(2 * DD);
    u16* Wcl = au16(2 * DD);
    u16* Wvh = au16(DD);
    u16* QKhb = au16((long long)S * 2 * D);
    u16* QKlb = au16((long long)S * 2 * D);
    u16* VTb = au16((long long)D * S);
    float* Lb = (float*)w;

    split_f32_kernel<true><<<2048, blk, 0, stream>>>(X, Xh, Xl, TOK * D);
    split_f32_kernel<true><<<512, blk, 0, stream>>>(Wq, Wch, Wcl, DD);
    split_f32_kernel<true><<<512, blk, 0, stream>>>(Wk, Wch + DD, Wcl + DD, DD);
    split_f32_kernel<false><<<512, blk, 0, stream>>>(Wv, Wvh, nullptr, DD);

    for (int b = 0; b < Bn; ++b) {
      const long long xo = (long long)b * S * D;
      gemmc<3, 1, 8><<<dim3(8, 8, 1), gblk, 0, stream>>>(
          Xh + xo, Xh + xo, Xl + xo, Wch, Wcl, Wch, nullptr, QKhb, QKlb,
          D, D, D, 2 * D, 0, 0, 0);
      gemmc<1, 2, 4><<<dim3(8, 8, 1), gblk, 0, stream>>>(
          Wvh, nullptr, nullptr, Xh + xo, nullptr, nullptr, nullptr, VTb,
          nullptr, D, D, D, S, 0, 0, 0);
      gemmc<3, 0, 4><<<dim3(8, 16, 1), gblk, 0, stream>>>(
          QKhb, QKhb, QKlb, QKhb + D, QKlb + D, QKhb + D,
          Lb, nullptr, nullptr, D, 2 * D, 2 * D, S, 0, 0, 0);
      softmax_inplace<<<dim3(S), blk, 0, stream>>>(Lb);
      gemmc<1, 0, 4><<<dim3(4, 16, 1), gblk, 0, stream>>>(
          (const u16*)Lb, nullptr, nullptr, VTb, nullptr, nullptr,
          out + xo, nullptr, nullptr, S, 2 * S, S, D, 0, 0, 0);
    }
  }
}

// Round 16
// 272.306 us; speedup vs baseline: 2.5077x; 1.4137x over previous
//
#include <hip/hip_runtime.h>
#include <math.h>

// SelfAttention B=4,S=2048,D=1024 fp32. Round 16 = r14 (385us, absmax 0.078)
// + ONE change: QKT uses fused 2-limb i8 GEMM g2 (stages Qa/Qb/Ka/Kb once
// per BK=64 tile; 604->402 MB staged) instead of concat-K gemmq. Arithmetic
// identical (accA = Qa.Ka, accC = Qa.Kb + Qb.Ka, same scales).
// Proj = gemmf (split-bf16 inputs, fused staging) -> i8 Q|K planes, r14-proven.

typedef unsigned short u16;
typedef signed char s8;
typedef __attribute__((ext_vector_type(8))) short bf16x8;
typedef __attribute__((ext_vector_type(4))) float f32x4;
typedef __attribute__((ext_vector_type(4))) int i32x4;

__device__ __forceinline__ u16 f2bf(float x) {
  unsigned u = __float_as_uint(x);
  unsigned r = (u + 0x7fffu + ((u >> 16) & 1u)) >> 16;
  return (u16)r;
}
__device__ __forceinline__ float bf2f(u16 h) {
  return __uint_as_float((unsigned)h << 16);
}
__device__ __forceinline__ int clamp127(int q) {
  return q < -127 ? -127 : (q > 127 ? 127 : q);
}

__device__ __forceinline__ void gload_lds16(const void* g, void* l) {
  __builtin_amdgcn_global_load_lds(
      (const __attribute__((address_space(1))) unsigned int*)(g),
      (__attribute__((address_space(3))) unsigned int*)(l), 16, 0, 0);
}

template <int N>
__device__ __forceinline__ void wait_vmcnt() {
  if constexpr (N == 0) asm volatile("s_waitcnt vmcnt(0)" ::: "memory");
  else if constexpr (N == 3) asm volatile("s_waitcnt vmcnt(3)" ::: "memory");
  else if constexpr (N == 4) asm volatile("s_waitcnt vmcnt(4)" ::: "memory");
  else if constexpr (N == 6) asm volatile("s_waitcnt vmcnt(6)" ::: "memory");
}

// fp32 -> hi bf16 (+ optional lo bf16), grid-stride, vectorized
template <bool LO>
__global__ __launch_bounds__(256) void split_f32_kernel(
    const float* __restrict__ in, u16* __restrict__ hi, u16* __restrict__ lo,
    long long n) {
  long long i = ((long long)blockIdx.x * 256 + threadIdx.x) * 4;
  const long long step = (long long)gridDim.x * 256 * 4;
  for (; i < n; i += step) {
    float4 x = *(const float4*)(in + i);
    float xs[4] = {x.x, x.y, x.z, x.w};
    u16 hv[4], lv[4];
#pragma unroll
    for (int j = 0; j < 4; j++) {
      hv[j] = f2bf(xs[j]);
      if (LO) lv[j] = f2bf(xs[j] - bf2f(hv[j]));
    }
    ushort4 h;
    h.x = hv[0]; h.y = hv[1]; h.z = hv[2]; h.w = hv[3];
    *(ushort4*)(hi + i) = h;
    if (LO) {
      ushort4 l;
      l.x = lv[0]; l.y = lv[1]; l.z = lv[2]; l.w = lv[3];
      *(ushort4*)(lo + i) = l;
    }
  }
}

// ===== fused-split projection (r14-proven): [Q|K](8192x2048) i8 2-limb
// planes from (Xh+Xl) @ (Wh+Wl)^T via hh+hl+lh. BM=BN=256, BK=32, 512 thr
// = 8 waves (2M x 4N), wave tile 128x64 (acc[8][4]). LDS: 2 slots x 4
// planes x 16KB = 128KB. Lead-1 ledger: stage(t+1) issued at tile-t start;
// 96 MFMA/wave covers load latency; end-of-tile vmcnt(0)+barrier.
__global__ __launch_bounds__(512, 2) void gemmf(
    const u16* __restrict__ Xh, const u16* __restrict__ Xl,
    const u16* __restrict__ Wh, const u16* __restrict__ Wl,
    s8* __restrict__ Ca, s8* __restrict__ Cb) {
  constexpr int PL = 8192;         // u16 per 256x32 plane
  __shared__ u16 lds[2 * 4 * PL];  // 128 KB

  const int tid = threadIdx.x;
  const int ln = tid & 63;
  const int wid = tid >> 6;
  const int wm = wid >> 2;  // 0..1
  const int wn = wid & 3;   // 0..3
  const int m0 = blockIdx.y * 256;
  const int n0 = blockIdx.x * 256;

  f32x4 acc[8][4];
  const f32x4 zero = {0.f, 0.f, 0.f, 0.f};
#pragma unroll
  for (int i = 0; i < 8; i++)
#pragma unroll
    for (int j = 0; j < 4; j++) acc[i][j] = zero;

  auto stage = [&](int t) {
    u16* slot = lds + (t & 1) * 4 * PL;
    const int k0 = t << 5;
#pragma unroll
    for (int l = 0; l < 2; ++l) {
      const int c = tid + l * 512;
      const int row = ((c >> 6) << 4) + (c & 15);
      const int kk = ((c >> 4) & 3) * 8;
      gload_lds16(Xh + (size_t)(m0 + row) * 1024 + k0 + kk, slot + c * 8);
      gload_lds16(Xl + (size_t)(m0 + row) * 1024 + k0 + kk,
                  slot + PL + c * 8);
      gload_lds16(Wh + (size_t)(n0 + row) * 1024 + k0 + kk,
                  slot + 2 * PL + c * 8);
      gload_lds16(Wl + (size_t)(n0 + row) * 1024 + k0 + kk,
                  slot + 3 * PL + c * 8);
    }
  };

  stage(0);
  wait_vmcnt<0>();
  __builtin_amdgcn_s_barrier();
  __builtin_amdgcn_sched_barrier(0);

  for (int t = 0; t < 32; ++t) {
    if (t + 1 < 32) stage(t + 1);
    const u16* Ah = lds + (t & 1) * 4 * PL;
    const u16* Al = Ah + PL;
    const u16* Bh = Ah + 2 * PL;
    const u16* Bl = Ah + 3 * PL;
    const int fo = ln * 8;
    bf16x8 bh[4], bl[4];
#pragma unroll
    for (int j = 0; j < 4; ++j) {
      bh[j] = *(const bf16x8*)(Bh + (wn * 4 + j) * 512 + fo);
      bl[j] = *(const bf16x8*)(Bl + (wn * 4 + j) * 512 + fo);
    }
    __builtin_amdgcn_s_setprio(1);
#pragma unroll
    for (int mh = 0; mh < 2; ++mh) {
      bf16x8 ah[4], al[4];
#pragma unroll
      for (int i = 0; i < 4; ++i) {
        ah[i] = *(const bf16x8*)(Ah + (wm * 8 + mh * 4 + i) * 512 + fo);
        al[i] = *(const bf16x8*)(Al + (wm * 8 + mh * 4 + i) * 512 + fo);
      }
#pragma unroll
      for (int i = 0; i < 4; ++i)
#pragma unroll
        for (int j = 0; j < 4; ++j) {
          f32x4 v = acc[mh * 4 + i][j];
          v = __builtin_amdgcn_mfma_f32_16x16x32_bf16(ah[i], bh[j], v, 0, 0, 0);
          v = __builtin_amdgcn_mfma_f32_16x16x32_bf16(ah[i], bl[j], v, 0, 0, 0);
          v = __builtin_amdgcn_mfma_f32_16x16x32_bf16(al[i], bh[j], v, 0, 0, 0);
          acc[mh * 4 + i][j] = v;
        }
    }
    __builtin_amdgcn_s_setprio(0);
    if (t + 1 < 32) {
      wait_vmcnt<0>();
      __builtin_amdgcn_s_barrier();
      __builtin_amdgcn_sched_barrier(0);
    }
  }

  const int orow = (ln >> 4) * 4;
  const int ocol = ln & 15;
#pragma unroll
  for (int mi = 0; mi < 8; ++mi)
#pragma unroll
    for (int ni = 0; ni < 4; ++ni) {
      const int rbase = m0 + wm * 128 + mi * 16 + orow;
      const int cc = n0 + wn * 64 + ni * 16 + ocol;
#pragma unroll
      for (int i = 0; i < 4; ++i) {
        const float v = acc[mi][ni][i];
        const long long off = (long long)(rbase + i) * 2048 + cc;
        const int qa = clamp127(__float2int_rn(v * 16.f));
        const int qb = clamp127(__float2int_rn((v - qa * 0.0625f) * 2048.f));
        Ca[off] = (s8)qa;
        Cb[off] = (s8)qb;
      }
    }
}

// ===== Fused 2-limb i8 NT GEMM (QKT): C = (Aa+Ab/128)·(Ba+Bb/128)^T via
// accA = Aa.Ba, accC = Aa.Bb + Ab.Ba; v = accA*scaleA + accC*scaleC.
// BM=128, BN=256, BK=64. 512 thr = 8 waves (2M x 4N), wave tile 64x64.
// LDS: 3 slots x [Aa 8K | Ab 8K | Ba 16K | Bb 16K] = 144 KB.
// Ledger (r9/r11-proven): stage lead 2, counted vmcnt(6), ONE barrier/tile.
// Subtile layout (bytes, validated r11-r14):
//   elem(row,k) at (row>>4)*1024+((k>>4)&3)*256+(row&15)*16+(k&15)
//   chunk c -> row=((c>>6)<<4)+(c&15), kk=((c>>4)&3)*16, dest=c*16 (linear)
//   frag: (ln>>4)*256+(ln&15)*16 -> i32x4, conflict-free.
__global__ __launch_bounds__(512, 2) void g2(
    const s8* __restrict__ Aa, const s8* __restrict__ Ab,
    const s8* __restrict__ Ba, const s8* __restrict__ Bb,
    u16* __restrict__ Ch, u16* __restrict__ Cl,
    int K, int lda, int ldb, int ldc,
    long long sA, long long sB, long long sC,
    float scaleA, float scaleC) {
  constexpr int APL = 128 * 64;   // bytes per A plane
  constexpr int BPL = 256 * 64;   // bytes per B plane
  constexpr int SLOT = 2 * APL + 2 * BPL;  // 49152
  __shared__ s8 lds[3 * SLOT];  // 144 KB

  const int tid = threadIdx.x;
  const int ln = tid & 63;
  const int wid = tid >> 6;
  const int wm = wid >> 2;  // 0..1
  const int wn = wid & 3;   // 0..3
  const int m0 = blockIdx.y * 128;
  const int n0 = blockIdx.x * 256;
  const int z = blockIdx.z;
  const long long za = (long long)z * sA;
  const long long zb = (long long)z * sB;

  const int NT = K >> 6;

  i32x4 accA[4][4], accC[4][4];
  const i32x4 izero = {0, 0, 0, 0};
#pragma unroll
  for (int i = 0; i < 4; i++)
#pragma unroll
    for (int j = 0; j < 4; j++) { accA[i][j] = izero; accC[i][j] = izero; }

  auto stage = [&](int t) {
    s8* slot = lds + (t % 3) * SLOT;
    const int k0 = t << 6;
    const s8* pAa = Aa + za + (size_t)m0 * lda + k0;
    const s8* pAb = Ab + za + (size_t)m0 * lda + k0;
    const s8* pBa = Ba + zb + (size_t)n0 * ldb + k0;
    const s8* pBb = Bb + zb + (size_t)n0 * ldb + k0;
    {  // A planes: 512 chunks each
      const int c = tid;
      const int row = ((c >> 6) << 4) + (c & 15);
      const int kk = ((c >> 4) & 3) * 16;
      gload_lds16(pAa + (size_t)row * lda + kk, slot + c * 16);
      gload_lds16(pAb + (size_t)row * lda + kk, slot + APL + c * 16);
    }
#pragma unroll
    for (int l = 0; l < 2; ++l) {  // B planes: 1024 chunks each
      const int c = tid + l * 512;
      const int row = ((c >> 6) << 4) + (c & 15);
      const int kk = ((c >> 4) & 3) * 16;
      gload_lds16(pBa + (size_t)row * ldb + kk, slot + 2 * APL + c * 16);
      gload_lds16(pBb + (size_t)row * ldb + kk,
                  slot + 2 * APL + BPL + c * 16);
    }
  };

  stage(0);
  stage(1);
  wait_vmcnt<6>();
  __builtin_amdgcn_s_barrier();
  __builtin_amdgcn_sched_barrier(0);

  for (int t = 0; t < NT; ++t) {
    if (t + 2 < NT) stage(t + 2);
    const s8* Sa = lds + (t % 3) * SLOT;
    const s8* Sb = Sa + APL;
    const s8* Sba = Sa + 2 * APL;
    const s8* Sbb = Sba + BPL;
    const int fo = (ln >> 4) * 256 + (ln & 15) * 16;
    i32x4 aa[4], ab[4], ba[4], bb[4];
#pragma unroll
    for (int j = 0; j < 4; ++j) {
      ba[j] = *(const i32x4*)(Sba + (wn * 4 + j) * 1024 + fo);
      bb[j] = *(const i32x4*)(Sbb + (wn * 4 + j) * 1024 + fo);
    }
#pragma unroll
    for (int i = 0; i < 4; ++i) {
      aa[i] = *(const i32x4*)(Sa + (wm * 4 + i) * 1024 + fo);
      ab[i] = *(const i32x4*)(Sb + (wm * 4 + i) * 1024 + fo);
    }
    __builtin_amdgcn_s_setprio(1);
#pragma unroll
    for (int i = 0; i < 4; ++i)
#pragma unroll
      for (int j = 0; j < 4; ++j) {
        accA[i][j] = __builtin_amdgcn_mfma_i32_16x16x64_i8(
            aa[i], ba[j], accA[i][j], 0, 0, 0);
        accC[i][j] = __builtin_amdgcn_mfma_i32_16x16x64_i8(
            aa[i], bb[j], accC[i][j], 0, 0, 0);
        accC[i][j] = __builtin_amdgcn_mfma_i32_16x16x64_i8(
            ab[i], ba[j], accC[i][j], 0, 0, 0);
      }
    __builtin_amdgcn_s_setprio(0);
    if (t + 1 < NT) {
      if (t + 2 < NT) wait_vmcnt<6>();
      else            wait_vmcnt<0>();
      __builtin_amdgcn_s_barrier();
      __builtin_amdgcn_sched_barrier(0);
    }
  }

  const int orow = (ln >> 4) * 4;
  const int ocol = ln & 15;
#pragma unroll
  for (int mi = 0; mi < 4; ++mi)
#pragma unroll
    for (int ni = 0; ni < 4; ++ni) {
      const int rbase = m0 + wm * 64 + mi * 16 + orow;
      const int cc = n0 + wn * 64 + ni * 16 + ocol;
#pragma unroll
      for (int i = 0; i < 4; ++i) {
        const float v = (float)accA[mi][ni][i] * scaleA +
                        (float)accC[mi][ni][i] * scaleC;
        const long long off =
            (long long)(rbase + i) * ldc + cc + (long long)z * sC;
        const u16 h = f2bf(v);
        Ch[off] = h;
        Cl[off] = f2bf(v - bf2f(h));
      }
    }
}

// ===== bf16 GEMM (r9/r11/r14-proven): NT over NSEG segs, BK=32, 3 slots,
// lead 2, counted vmcnt(L). BM=32*M_REP, BN=256, 512 thr = 8 waves.
// STORE: 0=f32, 1=split bf16, 2=bf16.
template <int NSEG, int STORE, int M_REP>
__global__ __launch_bounds__(512, 2) void gemmc(
    const u16* __restrict__ A0, const u16* __restrict__ A1,
    const u16* __restrict__ A2, const u16* __restrict__ B0,
    const u16* __restrict__ B1, const u16* __restrict__ B2,
    float* __restrict__ Cf, u16* __restrict__ Ch, u16* __restrict__ Cl,
    int Kseg, int lda, int ldb, int ldc,
    long long sA, long long sB, long long sC) {
  constexpr int BM = 32 * M_REP;
  constexpr int ASZ = BM * 32;   // u16
  constexpr int BSZ = 8192;      // 256x32 u16
  constexpr int SLOT = ASZ + BSZ;
  constexpr int LA = M_REP / 4;
  constexpr int L = LA + 2;
  __shared__ u16 lds[3 * SLOT];

  const int tid = threadIdx.x;
  const int ln = tid & 63;
  const int wid = tid >> 6;
  const int wm = wid >> 2;
  const int wn = wid & 3;
  const int m0 = blockIdx.y * BM;
  const int n0 = blockIdx.x * 256;
  const int z = blockIdx.z;
  const long long za = (long long)z * sA;
  const long long zb = (long long)z * sB;

  const int NT = NSEG * (Kseg >> 5);

  f32x4 acc[M_REP][4];
  const f32x4 zero = {0.f, 0.f, 0.f, 0.f};
#pragma unroll
  for (int i = 0; i < M_REP; i++)
#pragma unroll
    for (int j = 0; j < 4; j++) acc[i][j] = zero;

  auto baseA = [&](int t) -> const u16* {
    int kk = t << 5;
    const u16* p = A0;
    if (NSEG >= 2 && kk >= Kseg) { kk -= Kseg; p = A1; }
    if (NSEG >= 3 && kk >= Kseg) { kk -= Kseg; p = A2; }
    return p + za + (size_t)m0 * lda + kk;
  };
  auto baseB = [&](int t) -> const u16* {
    int kk = t << 5;
    const u16* p = B0;
    if (NSEG >= 2 && kk >= Kseg) { kk -= Kseg; p = B1; }
    if (NSEG >= 3 && kk >= Kseg) { kk -= Kseg; p = B2; }
    return p + zb + (size_t)n0 * ldb + kk;
  };
  auto stage = [&](int t) {
    u16* slot = lds + (t % 3) * SLOT;
    const u16* Ab = baseA(t);
    const u16* Bb = baseB(t);
#pragma unroll
    for (int l = 0; l < LA; ++l) {
      const int c = tid + l * 512;
      const int row = ((c >> 6) << 4) + (c & 15);
      const int kk = ((c >> 4) & 3) * 8;
      gload_lds16(Ab + (size_t)row * lda + kk, slot + c * 8);
    }
#pragma unroll
    for (int l = 0; l < 2; ++l) {
      const int c = tid + l * 512;
      const int row = ((c >> 6) << 4) + (c & 15);
      const int kk = ((c >> 4) & 3) * 8;
      gload_lds16(Bb + (size_t)row * ldb + kk, slot + ASZ + c * 8);
    }
  };

  stage(0);
  stage(1);
  wait_vmcnt<L>();
  __builtin_amdgcn_s_barrier();
  __builtin_amdgcn_sched_barrier(0);

  for (int t = 0; t < NT; ++t) {
    if (t + 2 < NT) stage(t + 2);
    const u16* Abuf = lds + (t % 3) * SLOT;
    const u16* Bbuf = Abuf + ASZ;
    const int fo = ln * 8;
    bf16x8 a[M_REP], b[4];
#pragma unroll
    for (int j = 0; j < 4; ++j)
      b[j] = *(const bf16x8*)(Bbuf + (wn * 4 + j) * 512 + fo);
#pragma unroll
    for (int i = 0; i < M_REP; ++i)
      a[i] = *(const bf16x8*)(Abuf + (wm * M_REP + i) * 512 + fo);
    __builtin_amdgcn_s_setprio(1);
#pragma unroll
    for (int i = 0; i < M_REP; ++i)
#pragma unroll
      for (int j = 0; j < 4; ++j)
        acc[i][j] = __builtin_amdgcn_mfma_f32_16x16x32_bf16(
            a[i], b[j], acc[i][j], 0, 0, 0);
    __builtin_amdgcn_s_setprio(0);
    if (t + 1 < NT) {
      if (t + 2 < NT) wait_vmcnt<L>();
      else            wait_vmcnt<0>();
      __builtin_amdgcn_s_barrier();
      __builtin_amdgcn_sched_barrier(0);
    }
  }

  const int orow = (ln >> 4) * 4;
  const int ocol = ln & 15;
#pragma unroll
  for (int mi = 0; mi < M_REP; ++mi)
#pragma unroll
    for (int ni = 0; ni < 4; ++ni) {
      const int rbase = m0 + wm * (M_REP * 16) + mi * 16 + orow;
      const int cc = n0 + wn * 64 + ni * 16 + ocol;
#pragma unroll
      for (int i = 0; i < 4; ++i) {
        const float v = acc[mi][ni][i];
        const long long off =
            (long long)(rbase + i) * ldc + cc + (long long)z * sC;
        if (STORE == 0) {
          Cf[off] = v;
        } else if (STORE == 1) {
          const u16 h = f2bf(v);
          Ch[off] = h;
          Cl[off] = f2bf(v - bf2f(h));
        } else {
          Ch[off] = f2bf(v);
        }
      }
    }
}

// ---- softmax (row = 2048) ----
__device__ __forceinline__ float blk_max(float v, float* red) {
  const int wv = threadIdx.x >> 6, lnn = threadIdx.x & 63;
#pragma unroll
  for (int off = 32; off; off >>= 1) v = fmaxf(v, __shfl_xor(v, off));
  if (lnn == 0) red[wv] = v;
  __syncthreads();
  return fmaxf(fmaxf(red[0], red[1]), fmaxf(red[2], red[3]));
}
__device__ __forceinline__ float blk_sum(float v, float* red) {
  const int wv = threadIdx.x >> 6, lnn = threadIdx.x & 63;
#pragma unroll
  for (int off = 32; off; off >>= 1) v += __shfl_xor(v, off);
  if (lnn == 0) red[wv] = v;
  __syncthreads();
  return red[0] + red[1] + red[2] + red[3];
}

// f32 L row -> bf16 P in place (row stride stays 4096 u16) [low tier]
__global__ __launch_bounds__(256) void softmax_inplace(float* __restrict__ L) {
  float* p = L + (size_t)blockIdx.x * 2048;
  const int t = threadIdx.x;
  __shared__ float redm[4];
  __shared__ float reds[4];
  float4 x0 = *(const float4*)(p + t * 4);
  float4 x1 = *(const float4*)(p + 1024 + t * 4);
  float m = fmaxf(fmaxf(fmaxf(x0.x, x0.y), fmaxf(x0.z, x0.w)),
                  fmaxf(fmaxf(x1.x, x1.y), fmaxf(x1.z, x1.w)));
  m = blk_max(m, redm);
  float e[8];
  e[0] = __expf(x0.x - m); e[1] = __expf(x0.y - m);
  e[2] = __expf(x0.z - m); e[3] = __expf(x0.w - m);
  e[4] = __expf(x1.x - m); e[5] = __expf(x1.y - m);
  e[6] = __expf(x1.z - m); e[7] = __expf(x1.w - m);
  float s = e[0] + e[1] + e[2] + e[3] + e[4] + e[5] + e[6] + e[7];
  s = blk_sum(s, reds);
  const float inv = 1.f / s;
  u16* q = (u16*)p;
  ushort4 o0, o1;
  o0.x = f2bf(e[0] * inv); o0.y = f2bf(e[1] * inv);
  o0.z = f2bf(e[2] * inv); o0.w = f2bf(e[3] * inv);
  o1.x = f2bf(e[4] * inv); o1.y = f2bf(e[5] * inv);
  o1.z = f2bf(e[6] * inv); o1.w = f2bf(e[7] * inv);
  *(ushort4*)(q + t * 4) = o0;
  *(ushort4*)(q + 1024 + t * 4) = o1;
}

// split-bf16 L (Lh+Ll) -> bf16 P over Lh row (stride 2048 u16)
__global__ __launch_bounds__(256) void softmax_split(
    u16* __restrict__ Lh, const u16* __restrict__ Ll) {
  u16* ph = Lh + (size_t)blockIdx.x * 2048;
  const u16* pl = Ll + (size_t)blockIdx.x * 2048;
  const int t = threadIdx.x;
  __shared__ float redm[4];
  __shared__ float reds[4];
  ushort4 h0 = *(const ushort4*)(ph + t * 4);
  ushort4 h1 = *(const ushort4*)(ph + 1024 + t * 4);
  ushort4 l0 = *(const ushort4*)(pl + t * 4);
  ushort4 l1 = *(const ushort4*)(pl + 1024 + t * 4);
  float x[8];
  x[0] = bf2f(h0.x) + bf2f(l0.x); x[1] = bf2f(h0.y) + bf2f(l0.y);
  x[2] = bf2f(h0.z) + bf2f(l0.z); x[3] = bf2f(h0.w) + bf2f(l0.w);
  x[4] = bf2f(h1.x) + bf2f(l1.x); x[5] = bf2f(h1.y) + bf2f(l1.y);
  x[6] = bf2f(h1.z) + bf2f(l1.z); x[7] = bf2f(h1.w) + bf2f(l1.w);
  float m = fmaxf(fmaxf(fmaxf(x[0], x[1]), fmaxf(x[2], x[3])),
                  fmaxf(fmaxf(x[4], x[5]), fmaxf(x[6], x[7])));
  m = blk_max(m, redm);
  float e[8];
#pragma unroll
  for (int j = 0; j < 8; ++j) e[j] = __expf(x[j] - m);
  float s = e[0] + e[1] + e[2] + e[3] + e[4] + e[5] + e[6] + e[7];
  s = blk_sum(s, reds);
  const float inv = 1.f / s;
  ushort4 o0, o1;
  o0.x = f2bf(e[0] * inv); o0.y = f2bf(e[1] * inv);
  o0.z = f2bf(e[2] * inv); o0.w = f2bf(e[3] * inv);
  o1.x = f2bf(e[4] * inv); o1.y = f2bf(e[5] * inv);
  o1.z = f2bf(e[6] * inv); o1.w = f2bf(e[7] * inv);
  *(ushort4*)(ph + t * 4) = o0;
  *(ushort4*)(ph + 1024 + t * 4) = o1;
}

extern "C" void kernel_launch(void* const* d_in, const int* in_sizes, int n_in,
                              void* d_out, int out_size, void* d_ws, size_t ws_size,
                              hipStream_t stream) {
  constexpr int Bn = 4, S = 2048, D = 1024;
  constexpr long long TOK = (long long)Bn * S;  // 8192
  constexpr long long DD = (long long)D * D;
  const float* X = (const float*)d_in[0];
  const float* Wq = (const float*)d_in[1];
  const float* Wk = (const float*)d_in[2];
  const float* Wv = (const float*)d_in[3];
  float* out = (float*)d_out;
  const dim3 blk(256);
  const dim3 gblk(512);

  char* w = (char*)d_ws;
  auto au16 = [&](long long n) { u16* p = (u16*)w; w += n * 2; return p; };
  auto as8 = [&](long long n) { s8* p = (s8*)w; w += n; return p; };

  if (ws_size >= (size_t)127926272ULL) {
    // Layout (127.93 MB): Xh Xl | Wch Wcl Wvh | QKa QKb (i8) | VT | Ll
    u16* Xh = au16(TOK * D);          // dead after VT -> hosts Lh
    u16* Xl = au16(TOK * D);
    u16* Wch = au16(2 * DD);
    u16* Wcl = au16(2 * DD);
    u16* Wvh = au16(DD);
    s8* QKa = as8(TOK * 2 * D);       // i8 hi plane, cols 0..1023=Q, rest=K
    s8* QKb = as8(TOK * 2 * D);       // i8 lo plane
    u16* VT = au16((long long)D * TOK);  // [1024][8192]
    u16* Ll = au16(TOK * S);          // logit lo plane (tail)
    u16* Lh = (u16*)d_ws;             // logit hi plane over dead X region

    split_f32_kernel<true><<<2048, blk, 0, stream>>>(X, Xh, Xl, TOK * D);
    split_f32_kernel<true><<<512, blk, 0, stream>>>(Wq, Wch, Wcl, DD);
    split_f32_kernel<true><<<512, blk, 0, stream>>>(Wk, Wch + DD, Wcl + DD, DD);
    split_f32_kernel<false><<<512, blk, 0, stream>>>(Wv, Wvh, nullptr, DD);

    // fused-split Q|K projection -> i8 planes: (8,32) = 256 blocks
    gemmf<<<dim3(8, 32, 1), gblk, 0, stream>>>(
        Xh, Xl, Wch, Wcl, QKa, QKb);
    // VT[e,tok] = Wvh . Xh^T : (32,8) = 256 blocks
    gemmc<1, 2, 4><<<dim3(32, 8, 1), gblk, 0, stream>>>(
        Wvh, nullptr, nullptr, Xh, nullptr, nullptr, nullptr, VT, nullptr,
        D, D, D, (int)TOK, 0, 0, 0);
    // X region dead now.

    // QKT fused-i8, one z=4 launch: (8,16,4) = 512 blocks
    // v = accA/256 + accC/32768   (q,k ~ a/16 + b/2048)
    g2<<<dim3(8, 16, 4), gblk, 0, stream>>>(
        QKa, QKb, QKa + D, QKb + D, Lh, Ll,
        D, 2 * D, 2 * D, S,
        (long long)S * 2 * D, (long long)S * 2 * D, (long long)S * S,
        3.90625e-3f, 3.0517578125e-5f);
    softmax_split<<<dim3(4 * S), blk, 0, stream>>>(Lh, Ll);
    // O = P . VT^T : (4,16,4) = 256 blocks
    gemmc<1, 0, 4><<<dim3(4, 16, 4), gblk, 0, stream>>>(
        Lh, nullptr, nullptr, VT, nullptr, nullptr,
        out, nullptr, nullptr, S, S, (int)TOK, D,
        (long long)S * S, (long long)S, (long long)S * D);
  } else {
    // Low tier (~82 MB): per-batch bf16 path (r9/r14)
    u16* Xh = au16(TOK * D);
    u16* Xl = au16(TOK * D);
    u16* Wch = au16(2 * DD);
    u16* Wcl = au16(2 * DD);
    u16* Wvh = au16(DD);
    u16* QKhb = au16((long long)S * 2 * D);
    u16* QKlb = au16((long long)S * 2 * D);
    u16* VTb = au16((long long)D * S);
    float* Lb = (float*)w;

    split_f32_kernel<true><<<2048, blk, 0, stream>>>(X, Xh, Xl, TOK * D);
    split_f32_kernel<true><<<512, blk, 0, stream>>>(Wq, Wch, Wcl, DD);
    split_f32_kernel<true><<<512, blk, 0, stream>>>(Wk, Wch + DD, Wcl + DD, DD);
    split_f32_kernel<false><<<512, blk, 0, stream>>>(Wv, Wvh, nullptr, DD);

    for (int b = 0; b < Bn; ++b) {
      const long long xo = (long long)b * S * D;
      gemmc<3, 1, 8><<<dim3(8, 8, 1), gblk, 0, stream>>>(
          Xh + xo, Xh + xo, Xl + xo, Wch, Wcl, Wch, nullptr, QKhb, QKlb,
          D, D, D, 2 * D, 0, 0, 0);
      gemmc<1, 2, 4><<<dim3(8, 8, 1), gblk, 0, stream>>>(
          Wvh, nullptr, nullptr, Xh + xo, nullptr, nullptr, nullptr, VTb,
          nullptr, D, D, D, S, 0, 0, 0);
      gemmc<3, 0, 4><<<dim3(8, 16, 1), gblk, 0, stream>>>(
          QKhb, QKhb, QKlb, QKhb + D, QKlb + D, QKhb + D,
          Lb, nullptr, nullptr, D, 2 * D, 2 * D, S, 0, 0, 0);
      softmax_inplace<<<dim3(S), blk, 0, stream>>>(Lb);
      gemmc<1, 0, 4><<<dim3(4, 16, 1), gblk, 0, stream>>>(
          (const u16*)Lb, nullptr, nullptr, VTb, nullptr, nullptr,
          out + xo, nullptr, nullptr, S, 2 * S, S, D, 0, 0, 0);
    }
  }
}

// Round 17
// 266.685 us; speedup vs baseline: 2.5606x; 1.0211x over previous
//
#include <hip/hip_runtime.h>
#include <math.h>

// SelfAttention B=4,S=2048,D=1024 fp32. Round 17 = r16 (272us, absmax 0.078)
// + bytes-neutral tweaks: PV & VT use BK=64 gemmc64 (32 MFMA/barrier, half
// the drains; staged bytes and accumulation order unchanged), W conversions
// merged into one z-dispatch launch. Proj gemmf / QKT g2 / softmax verbatim.

typedef unsigned short u16;
typedef signed char s8;
typedef __attribute__((ext_vector_type(8))) short bf16x8;
typedef __attribute__((ext_vector_type(4))) float f32x4;
typedef __attribute__((ext_vector_type(4))) int i32x4;

__device__ __forceinline__ u16 f2bf(float x) {
  unsigned u = __float_as_uint(x);
  unsigned r = (u + 0x7fffu + ((u >> 16) & 1u)) >> 16;
  return (u16)r;
}
__device__ __forceinline__ float bf2f(u16 h) {
  return __uint_as_float((unsigned)h << 16);
}
__device__ __forceinline__ int clamp127(int q) {
  return q < -127 ? -127 : (q > 127 ? 127 : q);
}

__device__ __forceinline__ void gload_lds16(const void* g, void* l) {
  __builtin_amdgcn_global_load_lds(
      (const __attribute__((address_space(1))) unsigned int*)(g),
      (__attribute__((address_space(3))) unsigned int*)(l), 16, 0, 0);
}

template <int N>
__device__ __forceinline__ void wait_vmcnt() {
  if constexpr (N == 0) asm volatile("s_waitcnt vmcnt(0)" ::: "memory");
  else if constexpr (N == 3) asm volatile("s_waitcnt vmcnt(3)" ::: "memory");
  else if constexpr (N == 4) asm volatile("s_waitcnt vmcnt(4)" ::: "memory");
  else if constexpr (N == 6) asm volatile("s_waitcnt vmcnt(6)" ::: "memory");
}

// fp32 -> hi bf16 (+ optional lo bf16), grid-stride, vectorized
template <bool LO>
__global__ __launch_bounds__(256) void split_f32_kernel(
    const float* __restrict__ in, u16* __restrict__ hi, u16* __restrict__ lo,
    long long n) {
  long long i = ((long long)blockIdx.x * 256 + threadIdx.x) * 4;
  const long long step = (long long)gridDim.x * 256 * 4;
  for (; i < n; i += step) {
    float4 x = *(const float4*)(in + i);
    float xs[4] = {x.x, x.y, x.z, x.w};
    u16 hv[4], lv[4];
#pragma unroll
    for (int j = 0; j < 4; j++) {
      hv[j] = f2bf(xs[j]);
      if (LO) lv[j] = f2bf(xs[j] - bf2f(hv[j]));
    }
    ushort4 h;
    h.x = hv[0]; h.y = hv[1]; h.z = hv[2]; h.w = hv[3];
    *(ushort4*)(hi + i) = h;
    if (LO) {
      ushort4 l;
      l.x = lv[0]; l.y = lv[1]; l.z = lv[2]; l.w = lv[3];
      *(ushort4*)(lo + i) = l;
    }
  }
}

// Merged W conversion: z=0 Wq->(Wch,Wcl), z=1 Wk->(Wch+DD,Wcl+DD),
// z=2 Wv->Wvh (hi only). n = DD per matrix.
__global__ __launch_bounds__(256) void quantW3_kernel(
    const float* __restrict__ Wq, const float* __restrict__ Wk,
    const float* __restrict__ Wv, u16* __restrict__ Wch,
    u16* __restrict__ Wcl, u16* __restrict__ Wvh, long long n) {
  const int z = blockIdx.z;
  const float* src = (z == 0) ? Wq : ((z == 1) ? Wk : Wv);
  u16* hi = (z == 0) ? Wch : ((z == 1) ? (Wch + n) : Wvh);
  u16* lo = (z == 0) ? Wcl : ((z == 1) ? (Wcl + n) : nullptr);
  long long i = ((long long)blockIdx.x * 256 + threadIdx.x) * 4;
  const long long step = (long long)gridDim.x * 256 * 4;
  for (; i < n; i += step) {
    float4 x = *(const float4*)(src + i);
    float xs[4] = {x.x, x.y, x.z, x.w};
    u16 hv[4], lv[4];
#pragma unroll
    for (int j = 0; j < 4; j++) {
      hv[j] = f2bf(xs[j]);
      lv[j] = f2bf(xs[j] - bf2f(hv[j]));
    }
    ushort4 h;
    h.x = hv[0]; h.y = hv[1]; h.z = hv[2]; h.w = hv[3];
    *(ushort4*)(hi + i) = h;
    if (z < 2) {
      ushort4 l;
      l.x = lv[0]; l.y = lv[1]; l.z = lv[2]; l.w = lv[3];
      *(ushort4*)(lo + i) = l;
    }
  }
}

// ===== fused-split projection (r14/r16-proven): [Q|K](8192x2048) i8 2-limb
// planes from (Xh+Xl) @ (Wh+Wl)^T via hh+hl+lh. BM=BN=256, BK=32, 512 thr
// = 8 waves (2M x 4N), wave tile 128x64. LDS: 2 slots x 4 planes x 16KB =
// 128KB. Lead-1 ledger: 96 MFMA/wave covers latency; vmcnt(0)+barrier/tile.
__global__ __launch_bounds__(512, 2) void gemmf(
    const u16* __restrict__ Xh, const u16* __restrict__ Xl,
    const u16* __restrict__ Wh, const u16* __restrict__ Wl,
    s8* __restrict__ Ca, s8* __restrict__ Cb) {
  constexpr int PL = 8192;         // u16 per 256x32 plane
  __shared__ u16 lds[2 * 4 * PL];  // 128 KB

  const int tid = threadIdx.x;
  const int ln = tid & 63;
  const int wid = tid >> 6;
  const int wm = wid >> 2;  // 0..1
  const int wn = wid & 3;   // 0..3
  const int m0 = blockIdx.y * 256;
  const int n0 = blockIdx.x * 256;

  f32x4 acc[8][4];
  const f32x4 zero = {0.f, 0.f, 0.f, 0.f};
#pragma unroll
  for (int i = 0; i < 8; i++)
#pragma unroll
    for (int j = 0; j < 4; j++) acc[i][j] = zero;

  auto stage = [&](int t) {
    u16* slot = lds + (t & 1) * 4 * PL;
    const int k0 = t << 5;
#pragma unroll
    for (int l = 0; l < 2; ++l) {
      const int c = tid + l * 512;
      const int row = ((c >> 6) << 4) + (c & 15);
      const int kk = ((c >> 4) & 3) * 8;
      gload_lds16(Xh + (size_t)(m0 + row) * 1024 + k0 + kk, slot + c * 8);
      gload_lds16(Xl + (size_t)(m0 + row) * 1024 + k0 + kk,
                  slot + PL + c * 8);
      gload_lds16(Wh + (size_t)(n0 + row) * 1024 + k0 + kk,
                  slot + 2 * PL + c * 8);
      gload_lds16(Wl + (size_t)(n0 + row) * 1024 + k0 + kk,
                  slot + 3 * PL + c * 8);
    }
  };

  stage(0);
  wait_vmcnt<0>();
  __builtin_amdgcn_s_barrier();
  __builtin_amdgcn_sched_barrier(0);

  for (int t = 0; t < 32; ++t) {
    if (t + 1 < 32) stage(t + 1);
    const u16* Ah = lds + (t & 1) * 4 * PL;
    const u16* Al = Ah + PL;
    const u16* Bh = Ah + 2 * PL;
    const u16* Bl = Ah + 3 * PL;
    const int fo = ln * 8;
    bf16x8 bh[4], bl[4];
#pragma unroll
    for (int j = 0; j < 4; ++j) {
      bh[j] = *(const bf16x8*)(Bh + (wn * 4 + j) * 512 + fo);
      bl[j] = *(const bf16x8*)(Bl + (wn * 4 + j) * 512 + fo);
    }
    __builtin_amdgcn_s_setprio(1);
#pragma unroll
    for (int mh = 0; mh < 2; ++mh) {
      bf16x8 ah[4], al[4];
#pragma unroll
      for (int i = 0; i < 4; ++i) {
        ah[i] = *(const bf16x8*)(Ah + (wm * 8 + mh * 4 + i) * 512 + fo);
        al[i] = *(const bf16x8*)(Al + (wm * 8 + mh * 4 + i) * 512 + fo);
      }
#pragma unroll
      for (int i = 0; i < 4; ++i)
#pragma unroll
        for (int j = 0; j < 4; ++j) {
          f32x4 v = acc[mh * 4 + i][j];
          v = __builtin_amdgcn_mfma_f32_16x16x32_bf16(ah[i], bh[j], v, 0, 0, 0);
          v = __builtin_amdgcn_mfma_f32_16x16x32_bf16(ah[i], bl[j], v, 0, 0, 0);
          v = __builtin_amdgcn_mfma_f32_16x16x32_bf16(al[i], bh[j], v, 0, 0, 0);
          acc[mh * 4 + i][j] = v;
        }
    }
    __builtin_amdgcn_s_setprio(0);
    if (t + 1 < 32) {
      wait_vmcnt<0>();
      __builtin_amdgcn_s_barrier();
      __builtin_amdgcn_sched_barrier(0);
    }
  }

  const int orow = (ln >> 4) * 4;
  const int ocol = ln & 15;
#pragma unroll
  for (int mi = 0; mi < 8; ++mi)
#pragma unroll
    for (int ni = 0; ni < 4; ++ni) {
      const int rbase = m0 + wm * 128 + mi * 16 + orow;
      const int cc = n0 + wn * 64 + ni * 16 + ocol;
#pragma unroll
      for (int i = 0; i < 4; ++i) {
        const float v = acc[mi][ni][i];
        const long long off = (long long)(rbase + i) * 2048 + cc;
        const int qa = clamp127(__float2int_rn(v * 16.f));
        const int qb = clamp127(__float2int_rn((v - qa * 0.0625f) * 2048.f));
        Ca[off] = (s8)qa;
        Cb[off] = (s8)qb;
      }
    }
}

// ===== Fused 2-limb i8 NT GEMM (QKT, r16-proven): C=(Aa+Ab/128)(Ba+Bb/128)^T
// via accA=Aa.Ba, accC=Aa.Bb+Ab.Ba; v = accA*scaleA + accC*scaleC.
// BM=128, BN=256, BK=64. LDS: 3 slots x 48KB. Lead 2, counted vmcnt(6).
__global__ __launch_bounds__(512, 2) void g2(
    const s8* __restrict__ Aa, const s8* __restrict__ Ab,
    const s8* __restrict__ Ba, const s8* __restrict__ Bb,
    u16* __restrict__ Ch, u16* __restrict__ Cl,
    int K, int lda, int ldb, int ldc,
    long long sA, long long sB, long long sC,
    float scaleA, float scaleC) {
  constexpr int APL = 128 * 64;   // bytes per A plane
  constexpr int BPL = 256 * 64;   // bytes per B plane
  constexpr int SLOT = 2 * APL + 2 * BPL;  // 49152
  __shared__ s8 lds[3 * SLOT];  // 144 KB

  const int tid = threadIdx.x;
  const int ln = tid & 63;
  const int wid = tid >> 6;
  const int wm = wid >> 2;  // 0..1
  const int wn = wid & 3;   // 0..3
  const int m0 = blockIdx.y * 128;
  const int n0 = blockIdx.x * 256;
  const int z = blockIdx.z;
  const long long za = (long long)z * sA;
  const long long zb = (long long)z * sB;

  const int NT = K >> 6;

  i32x4 accA[4][4], accC[4][4];
  const i32x4 izero = {0, 0, 0, 0};
#pragma unroll
  for (int i = 0; i < 4; i++)
#pragma unroll
    for (int j = 0; j < 4; j++) { accA[i][j] = izero; accC[i][j] = izero; }

  auto stage = [&](int t) {
    s8* slot = lds + (t % 3) * SLOT;
    const int k0 = t << 6;
    const s8* pAa = Aa + za + (size_t)m0 * lda + k0;
    const s8* pAb = Ab + za + (size_t)m0 * lda + k0;
    const s8* pBa = Ba + zb + (size_t)n0 * ldb + k0;
    const s8* pBb = Bb + zb + (size_t)n0 * ldb + k0;
    {
      const int c = tid;
      const int row = ((c >> 6) << 4) + (c & 15);
      const int kk = ((c >> 4) & 3) * 16;
      gload_lds16(pAa + (size_t)row * lda + kk, slot + c * 16);
      gload_lds16(pAb + (size_t)row * lda + kk, slot + APL + c * 16);
    }
#pragma unroll
    for (int l = 0; l < 2; ++l) {
      const int c = tid + l * 512;
      const int row = ((c >> 6) << 4) + (c & 15);
      const int kk = ((c >> 4) & 3) * 16;
      gload_lds16(pBa + (size_t)row * ldb + kk, slot + 2 * APL + c * 16);
      gload_lds16(pBb + (size_t)row * ldb + kk,
                  slot + 2 * APL + BPL + c * 16);
    }
  };

  stage(0);
  stage(1);
  wait_vmcnt<6>();
  __builtin_amdgcn_s_barrier();
  __builtin_amdgcn_sched_barrier(0);

  for (int t = 0; t < NT; ++t) {
    if (t + 2 < NT) stage(t + 2);
    const s8* Sa = lds + (t % 3) * SLOT;
    const s8* Sb = Sa + APL;
    const s8* Sba = Sa + 2 * APL;
    const s8* Sbb = Sba + BPL;
    const int fo = (ln >> 4) * 256 + (ln & 15) * 16;
    i32x4 aa[4], ab[4], ba[4], bb[4];
#pragma unroll
    for (int j = 0; j < 4; ++j) {
      ba[j] = *(const i32x4*)(Sba + (wn * 4 + j) * 1024 + fo);
      bb[j] = *(const i32x4*)(Sbb + (wn * 4 + j) * 1024 + fo);
    }
#pragma unroll
    for (int i = 0; i < 4; ++i) {
      aa[i] = *(const i32x4*)(Sa + (wm * 4 + i) * 1024 + fo);
      ab[i] = *(const i32x4*)(Sb + (wm * 4 + i) * 1024 + fo);
    }
    __builtin_amdgcn_s_setprio(1);
#pragma unroll
    for (int i = 0; i < 4; ++i)
#pragma unroll
      for (int j = 0; j < 4; ++j) {
        accA[i][j] = __builtin_amdgcn_mfma_i32_16x16x64_i8(
            aa[i], ba[j], accA[i][j], 0, 0, 0);
        accC[i][j] = __builtin_amdgcn_mfma_i32_16x16x64_i8(
            aa[i], bb[j], accC[i][j], 0, 0, 0);
        accC[i][j] = __builtin_amdgcn_mfma_i32_16x16x64_i8(
            ab[i], ba[j], accC[i][j], 0, 0, 0);
      }
    __builtin_amdgcn_s_setprio(0);
    if (t + 1 < NT) {
      if (t + 2 < NT) wait_vmcnt<6>();
      else            wait_vmcnt<0>();
      __builtin_amdgcn_s_barrier();
      __builtin_amdgcn_sched_barrier(0);
    }
  }

  const int orow = (ln >> 4) * 4;
  const int ocol = ln & 15;
#pragma unroll
  for (int mi = 0; mi < 4; ++mi)
#pragma unroll
    for (int ni = 0; ni < 4; ++ni) {
      const int rbase = m0 + wm * 64 + mi * 16 + orow;
      const int cc = n0 + wn * 64 + ni * 16 + ocol;
#pragma unroll
      for (int i = 0; i < 4; ++i) {
        const float v = (float)accA[mi][ni][i] * scaleA +
                        (float)accC[mi][ni][i] * scaleC;
        const long long off =
            (long long)(rbase + i) * ldc + cc + (long long)z * sC;
        const u16 h = f2bf(v);
        Ch[off] = h;
        Cl[off] = f2bf(v - bf2f(h));
      }
    }
}

// ===== bf16 NT GEMM, BK=64 (r12-validated layout), BM=128, BN=256.
// 512 thr = 8 waves (2M x 4N); 32 MFMA/wave/tile. LDS 3 slots x 48KB.
// r9 ledger: stage lead 2, counted vmcnt(6), one barrier per tile.
// Subtile (u16): elem(row,k) at (row>>4)*1024+((k>>3)&7)*128+(row&15)*8+(k&7)
//   chunk c -> row=((c>>7)<<4)+(c&15), kk=((c>>4)&7)*8; dest=c*8 (linear).
//   frag (k-half h): rb*1024 + h*512 + ln*8 -> conflict-free b128.
// STORE: 0=f32 Cf, 2=bf16 Ch.
template <int STORE>
__global__ __launch_bounds__(512, 2) void gemmc64(
    const u16* __restrict__ A0, const u16* __restrict__ B0,
    float* __restrict__ Cf, u16* __restrict__ Ch,
    int K, int lda, int ldb, int ldc,
    long long sA, long long sB, long long sC) {
  constexpr int ASZ = 128 * 64;  // u16
  constexpr int BSZ = 256 * 64;  // u16
  constexpr int SLOT = ASZ + BSZ;
  __shared__ u16 lds[3 * SLOT];  // 144 KB

  const int tid = threadIdx.x;
  const int ln = tid & 63;
  const int wid = tid >> 6;
  const int wm = wid >> 2;
  const int wn = wid & 3;
  const int m0 = blockIdx.y * 128;
  const int n0 = blockIdx.x * 256;
  const int z = blockIdx.z;
  const long long za = (long long)z * sA;
  const long long zb = (long long)z * sB;

  const int NT = K >> 6;

  f32x4 acc[4][4];
  const f32x4 zero = {0.f, 0.f, 0.f, 0.f};
#pragma unroll
  for (int i = 0; i < 4; i++)
#pragma unroll
    for (int j = 0; j < 4; j++) acc[i][j] = zero;

  auto stage = [&](int t) {
    u16* slot = lds + (t % 3) * SLOT;
    const int k0 = t << 6;
    const u16* Ab = A0 + za + (size_t)m0 * lda + k0;
    const u16* Bb = B0 + zb + (size_t)n0 * ldb + k0;
#pragma unroll
    for (int l = 0; l < 2; ++l) {  // A: 1024 chunks
      const int c = tid + l * 512;
      const int row = ((c >> 7) << 4) + (c & 15);
      const int kk = ((c >> 4) & 7) * 8;
      gload_lds16(Ab + (size_t)row * lda + kk, slot + c * 8);
    }
#pragma unroll
    for (int l = 0; l < 4; ++l) {  // B: 2048 chunks
      const int c = tid + l * 512;
      const int row = ((c >> 7) << 4) + (c & 15);
      const int kk = ((c >> 4) & 7) * 8;
      gload_lds16(Bb + (size_t)row * ldb + kk, slot + ASZ + c * 8);
    }
  };

  stage(0);
  stage(1);
  wait_vmcnt<6>();
  __builtin_amdgcn_s_barrier();
  __builtin_amdgcn_sched_barrier(0);

  for (int t = 0; t < NT; ++t) {
    if (t + 2 < NT) stage(t + 2);
    const u16* Abuf = lds + (t % 3) * SLOT;
    const u16* Bbuf = Abuf + ASZ;
    const int fo = ln * 8;
    bf16x8 a0[4], a1[4], b0[4], b1[4];
#pragma unroll
    for (int j = 0; j < 4; ++j) {
      b0[j] = *(const bf16x8*)(Bbuf + (wn * 4 + j) * 1024 + fo);
      b1[j] = *(const bf16x8*)(Bbuf + (wn * 4 + j) * 1024 + 512 + fo);
    }
#pragma unroll
    for (int i = 0; i < 4; ++i) {
      a0[i] = *(const bf16x8*)(Abuf + (wm * 4 + i) * 1024 + fo);
      a1[i] = *(const bf16x8*)(Abuf + (wm * 4 + i) * 1024 + 512 + fo);
    }
    __builtin_amdgcn_s_setprio(1);
#pragma unroll
    for (int i = 0; i < 4; ++i)
#pragma unroll
      for (int j = 0; j < 4; ++j) {
        acc[i][j] = __builtin_amdgcn_mfma_f32_16x16x32_bf16(
            a0[i], b0[j], acc[i][j], 0, 0, 0);
        acc[i][j] = __builtin_amdgcn_mfma_f32_16x16x32_bf16(
            a1[i], b1[j], acc[i][j], 0, 0, 0);
      }
    __builtin_amdgcn_s_setprio(0);
    if (t + 1 < NT) {
      if (t + 2 < NT) wait_vmcnt<6>();
      else            wait_vmcnt<0>();
      __builtin_amdgcn_s_barrier();
      __builtin_amdgcn_sched_barrier(0);
    }
  }

  const int orow = (ln >> 4) * 4;
  const int ocol = ln & 15;
#pragma unroll
  for (int mi = 0; mi < 4; ++mi)
#pragma unroll
    for (int ni = 0; ni < 4; ++ni) {
      const int rbase = m0 + wm * 64 + mi * 16 + orow;
      const int cc = n0 + wn * 64 + ni * 16 + ocol;
#pragma unroll
      for (int i = 0; i < 4; ++i) {
        const float v = acc[mi][ni][i];
        const long long off =
            (long long)(rbase + i) * ldc + cc + (long long)z * sC;
        if (STORE == 0) Cf[off] = v;
        else            Ch[off] = f2bf(v);
      }
    }
}

// ===== bf16 GEMM BK=32 (r9-proven) — kept for the low tier only.
template <int NSEG, int STORE, int M_REP>
__global__ __launch_bounds__(512, 2) void gemmc(
    const u16* __restrict__ A0, const u16* __restrict__ A1,
    const u16* __restrict__ A2, const u16* __restrict__ B0,
    const u16* __restrict__ B1, const u16* __restrict__ B2,
    float* __restrict__ Cf, u16* __restrict__ Ch, u16* __restrict__ Cl,
    int Kseg, int lda, int ldb, int ldc,
    long long sA, long long sB, long long sC) {
  constexpr int BM = 32 * M_REP;
  constexpr int ASZ = BM * 32;
  constexpr int BSZ = 8192;
  constexpr int SLOT = ASZ + BSZ;
  constexpr int LA = M_REP / 4;
  constexpr int L = LA + 2;
  __shared__ u16 lds[3 * SLOT];

  const int tid = threadIdx.x;
  const int ln = tid & 63;
  const int wid = tid >> 6;
  const int wm = wid >> 2;
  const int wn = wid & 3;
  const int m0 = blockIdx.y * BM;
  const int n0 = blockIdx.x * 256;
  const int z = blockIdx.z;
  const long long za = (long long)z * sA;
  const long long zb = (long long)z * sB;

  const int NT = NSEG * (Kseg >> 5);

  f32x4 acc[M_REP][4];
  const f32x4 zero = {0.f, 0.f, 0.f, 0.f};
#pragma unroll
  for (int i = 0; i < M_REP; i++)
#pragma unroll
    for (int j = 0; j < 4; j++) acc[i][j] = zero;

  auto baseA = [&](int t) -> const u16* {
    int kk = t << 5;
    const u16* p = A0;
    if (NSEG >= 2 && kk >= Kseg) { kk -= Kseg; p = A1; }
    if (NSEG >= 3 && kk >= Kseg) { kk -= Kseg; p = A2; }
    return p + za + (size_t)m0 * lda + kk;
  };
  auto baseB = [&](int t) -> const u16* {
    int kk = t << 5;
    const u16* p = B0;
    if (NSEG >= 2 && kk >= Kseg) { kk -= Kseg; p = B1; }
    if (NSEG >= 3 && kk >= Kseg) { kk -= Kseg; p = B2; }
    return p + zb + (size_t)n0 * ldb + kk;
  };
  auto stage = [&](int t) {
    u16* slot = lds + (t % 3) * SLOT;
    const u16* Ab = baseA(t);
    const u16* Bb = baseB(t);
#pragma unroll
    for (int l = 0; l < LA; ++l) {
      const int c = tid + l * 512;
      const int row = ((c >> 6) << 4) + (c & 15);
      const int kk = ((c >> 4) & 3) * 8;
      gload_lds16(Ab + (size_t)row * lda + kk, slot + c * 8);
    }
#pragma unroll
    for (int l = 0; l < 2; ++l) {
      const int c = tid + l * 512;
      const int row = ((c >> 6) << 4) + (c & 15);
      const int kk = ((c >> 4) & 3) * 8;
      gload_lds16(Bb + (size_t)row * ldb + kk, slot + ASZ + c * 8);
    }
  };

  stage(0);
  stage(1);
  wait_vmcnt<L>();
  __builtin_amdgcn_s_barrier();
  __builtin_amdgcn_sched_barrier(0);

  for (int t = 0; t < NT; ++t) {
    if (t + 2 < NT) stage(t + 2);
    const u16* Abuf = lds + (t % 3) * SLOT;
    const u16* Bbuf = Abuf + ASZ;
    const int fo = ln * 8;
    bf16x8 a[M_REP], b[4];
#pragma unroll
    for (int j = 0; j < 4; ++j)
      b[j] = *(const bf16x8*)(Bbuf + (wn * 4 + j) * 512 + fo);
#pragma unroll
    for (int i = 0; i < M_REP; ++i)
      a[i] = *(const bf16x8*)(Abuf + (wm * M_REP + i) * 512 + fo);
    __builtin_amdgcn_s_setprio(1);
#pragma unroll
    for (int i = 0; i < M_REP; ++i)
#pragma unroll
      for (int j = 0; j < 4; ++j)
        acc[i][j] = __builtin_amdgcn_mfma_f32_16x16x32_bf16(
            a[i], b[j], acc[i][j], 0, 0, 0);
    __builtin_amdgcn_s_setprio(0);
    if (t + 1 < NT) {
      if (t + 2 < NT) wait_vmcnt<L>();
      else            wait_vmcnt<0>();
      __builtin_amdgcn_s_barrier();
      __builtin_amdgcn_sched_barrier(0);
    }
  }

  const int orow = (ln >> 4) * 4;
  const int ocol = ln & 15;
#pragma unroll
  for (int mi = 0; mi < M_REP; ++mi)
#pragma unroll
    for (int ni = 0; ni < 4; ++ni) {
      const int rbase = m0 + wm * (M_REP * 16) + mi * 16 + orow;
      const int cc = n0 + wn * 64 + ni * 16 + ocol;
#pragma unroll
      for (int i = 0; i < 4; ++i) {
        const float v = acc[mi][ni][i];
        const long long off =
            (long long)(rbase + i) * ldc + cc + (long long)z * sC;
        if (STORE == 0) {
          Cf[off] = v;
        } else if (STORE == 1) {
          const u16 h = f2bf(v);
          Ch[off] = h;
          Cl[off] = f2bf(v - bf2f(h));
        } else {
          Ch[off] = f2bf(v);
        }
      }
    }
}

// ---- softmax (row = 2048) ----
__device__ __forceinline__ float blk_max(float v, float* red) {
  const int wv = threadIdx.x >> 6, lnn = threadIdx.x & 63;
#pragma unroll
  for (int off = 32; off; off >>= 1) v = fmaxf(v, __shfl_xor(v, off));
  if (lnn == 0) red[wv] = v;
  __syncthreads();
  return fmaxf(fmaxf(red[0], red[1]), fmaxf(red[2], red[3]));
}
__device__ __forceinline__ float blk_sum(float v, float* red) {
  const int wv = threadIdx.x >> 6, lnn = threadIdx.x & 63;
#pragma unroll
  for (int off = 32; off; off >>= 1) v += __shfl_xor(v, off);
  if (lnn == 0) red[wv] = v;
  __syncthreads();
  return red[0] + red[1] + red[2] + red[3];
}

// f32 L row -> bf16 P in place (row stride stays 4096 u16) [low tier]
__global__ __launch_bounds__(256) void softmax_inplace(float* __restrict__ L) {
  float* p = L + (size_t)blockIdx.x * 2048;
  const int t = threadIdx.x;
  __shared__ float redm[4];
  __shared__ float reds[4];
  float4 x0 = *(const float4*)(p + t * 4);
  float4 x1 = *(const float4*)(p + 1024 + t * 4);
  float m = fmaxf(fmaxf(fmaxf(x0.x, x0.y), fmaxf(x0.z, x0.w)),
                  fmaxf(fmaxf(x1.x, x1.y), fmaxf(x1.z, x1.w)));
  m = blk_max(m, redm);
  float e[8];
  e[0] = __expf(x0.x - m); e[1] = __expf(x0.y - m);
  e[2] = __expf(x0.z - m); e[3] = __expf(x0.w - m);
  e[4] = __expf(x1.x - m); e[5] = __expf(x1.y - m);
  e[6] = __expf(x1.z - m); e[7] = __expf(x1.w - m);
  float s = e[0] + e[1] + e[2] + e[3] + e[4] + e[5] + e[6] + e[7];
  s = blk_sum(s, reds);
  const float inv = 1.f / s;
  u16* q = (u16*)p;
  ushort4 o0, o1;
  o0.x = f2bf(e[0] * inv); o0.y = f2bf(e[1] * inv);
  o0.z = f2bf(e[2] * inv); o0.w = f2bf(e[3] * inv);
  o1.x = f2bf(e[4] * inv); o1.y = f2bf(e[5] * inv);
  o1.z = f2bf(e[6] * inv); o1.w = f2bf(e[7] * inv);
  *(ushort4*)(q + t * 4) = o0;
  *(ushort4*)(q + 1024 + t * 4) = o1;
}

// split-bf16 L (Lh+Ll) -> bf16 P over Lh row (stride 2048 u16)
__global__ __launch_bounds__(256) void softmax_split(
    u16* __restrict__ Lh, const u16* __restrict__ Ll) {
  u16* ph = Lh + (size_t)blockIdx.x * 2048;
  const u16* pl = Ll + (size_t)blockIdx.x * 2048;
  const int t = threadIdx.x;
  __shared__ float redm[4];
  __shared__ float reds[4];
  ushort4 h0 = *(const ushort4*)(ph + t * 4);
  ushort4 h1 = *(const ushort4*)(ph + 1024 + t * 4);
  ushort4 l0 = *(const ushort4*)(pl + t * 4);
  ushort4 l1 = *(const ushort4*)(pl + 1024 + t * 4);
  float x[8];
  x[0] = bf2f(h0.x) + bf2f(l0.x); x[1] = bf2f(h0.y) + bf2f(l0.y);
  x[2] = bf2f(h0.z) + bf2f(l0.z); x[3] = bf2f(h0.w) + bf2f(l0.w);
  x[4] = bf2f(h1.x) + bf2f(l1.x); x[5] = bf2f(h1.y) + bf2f(l1.y);
  x[6] = bf2f(h1.z) + bf2f(l1.z); x[7] = bf2f(h1.w) + bf2f(l1.w);
  float m = fmaxf(fmaxf(fmaxf(x[0], x[1]), fmaxf(x[2], x[3])),
                  fmaxf(fmaxf(x[4], x[5]), fmaxf(x[6], x[7])));
  m = blk_max(m, redm);
  float e[8];
#pragma unroll
  for (int j = 0; j < 8; ++j) e[j] = __expf(x[j] - m);
  float s = e[0] + e[1] + e[2] + e[3] + e[4] + e[5] + e[6] + e[7];
  s = blk_sum(s, reds);
  const float inv = 1.f / s;
  ushort4 o0, o1;
  o0.x = f2bf(e[0] * inv); o0.y = f2bf(e[1] * inv);
  o0.z = f2bf(e[2] * inv); o0.w = f2bf(e[3] * inv);
  o1.x = f2bf(e[4] * inv); o1.y = f2bf(e[5] * inv);
  o1.z = f2bf(e[6] * inv); o1.w = f2bf(e[7] * inv);
  *(ushort4*)(ph + t * 4) = o0;
  *(ushort4*)(ph + 1024 + t * 4) = o1;
}

extern "C" void kernel_launch(void* const* d_in, const int* in_sizes, int n_in,
                              void* d_out, int out_size, void* d_ws, size_t ws_size,
                              hipStream_t stream) {
  constexpr int Bn = 4, S = 2048, D = 1024;
  constexpr long long TOK = (long long)Bn * S;  // 8192
  constexpr long long DD = (long long)D * D;
  const float* X = (const float*)d_in[0];
  const float* Wq = (const float*)d_in[1];
  const float* Wk = (const float*)d_in[2];
  const float* Wv = (const float*)d_in[3];
  float* out = (float*)d_out;
  const dim3 blk(256);
  const dim3 gblk(512);

  char* w = (char*)d_ws;
  auto au16 = [&](long long n) { u16* p = (u16*)w; w += n * 2; return p; };
  auto as8 = [&](long long n) { s8* p = (s8*)w; w += n; return p; };

  if (ws_size >= (size_t)127926272ULL) {
    // Layout (127.93 MB): Xh Xl | Wch Wcl Wvh | QKa QKb (i8) | VT | Ll
    u16* Xh = au16(TOK * D);          // dead after VT -> hosts Lh
    u16* Xl = au16(TOK * D);
    u16* Wch = au16(2 * DD);
    u16* Wcl = au16(2 * DD);
    u16* Wvh = au16(DD);
    s8* QKa = as8(TOK * 2 * D);       // i8 hi plane, cols 0..1023=Q, rest=K
    s8* QKb = as8(TOK * 2 * D);       // i8 lo plane
    u16* VT = au16((long long)D * TOK);  // [1024][8192]
    u16* Ll = au16(TOK * S);          // logit lo plane (tail)
    u16* Lh = (u16*)d_ws;             // logit hi plane over dead X region

    split_f32_kernel<true><<<2048, blk, 0, stream>>>(X, Xh, Xl, TOK * D);
    quantW3_kernel<<<dim3(256, 1, 3), blk, 0, stream>>>(
        Wq, Wk, Wv, Wch, Wcl, Wvh, DD);

    // fused-split Q|K projection -> i8 planes: (8,32) = 256 blocks
    gemmf<<<dim3(8, 32, 1), gblk, 0, stream>>>(
        Xh, Xl, Wch, Wcl, QKa, QKb);
    // VT[e,tok] = Wvh . Xh^T : BK=64, (32,8) = 256 blocks
    gemmc64<2><<<dim3(32, 8, 1), gblk, 0, stream>>>(
        Wvh, Xh, nullptr, VT, D, D, D, (int)TOK, 0, 0, 0);
    // X region dead now.

    // QKT fused-i8, one z=4 launch: (8,16,4) = 512 blocks
    g2<<<dim3(8, 16, 4), gblk, 0, stream>>>(
        QKa, QKb, QKa + D, QKb + D, Lh, Ll,
        D, 2 * D, 2 * D, S,
        (long long)S * 2 * D, (long long)S * 2 * D, (long long)S * S,
        3.90625e-3f, 3.0517578125e-5f);
    softmax_split<<<dim3(4 * S), blk, 0, stream>>>(Lh, Ll);
    // O = P . VT^T : BK=64, (4,16,4) = 256 blocks
    gemmc64<0><<<dim3(4, 16, 4), gblk, 0, stream>>>(
        Lh, VT, out, nullptr, S, S, (int)TOK, D,
        (long long)S * S, (long long)S, (long long)S * D);
  } else {
    // Low tier (~82 MB): per-batch bf16 path (r9/r16)
    u16* Xh = au16(TOK * D);
    u16* Xl = au16(TOK * D);
    u16* Wch = au16(2 * DD);
    u16* Wcl = au16(2 * DD);
    u16* Wvh = au16(DD);
    u16* QKhb = au16((long long)S * 2 * D);
    u16* QKlb = au16((long long)S * 2 * D);
    u16* VTb = au16((long long)D * S);
    float* Lb = (float*)w;

    split_f32_kernel<true><<<2048, blk, 0, stream>>>(X, Xh, Xl, TOK * D);
    split_f32_kernel<true><<<512, blk, 0, stream>>>(Wq, Wch, Wcl, DD);
    split_f32_kernel<true><<<512, blk, 0, stream>>>(Wk, Wch + DD, Wcl + DD, DD);
    split_f32_kernel<false><<<512, blk, 0, stream>>>(Wv, Wvh, nullptr, DD);

    for (int b = 0; b < Bn; ++b) {
      const long long xo = (long long)b * S * D;
      gemmc<3, 1, 8><<<dim3(8, 8, 1), gblk, 0, stream>>>(
          Xh + xo, Xh + xo, Xl + xo, Wch, Wcl, Wch, nullptr, QKhb, QKlb,
          D, D, D, 2 * D, 0, 0, 0);
      gemmc<1, 2, 4><<<dim3(8, 8, 1), gblk, 0, stream>>>(
          Wvh, nullptr, nullptr, Xh + xo, nullptr, nullptr, nullptr, VTb,
          nullptr, D, D, D, S, 0, 0, 0);
      gemmc<3, 0, 4><<<dim3(8, 16, 1), gblk, 0, stream>>>(
          QKhb, QKhb, QKlb, QKhb + D, QKlb + D, QKhb + D,
          Lb, nullptr, nullptr, D, 2 * D, 2 * D, S, 0, 0, 0);
      softmax_inplace<<<dim3(S), blk, 0, stream>>>(Lb);
      gemmc<1, 0, 4><<<dim3(4, 16, 1), gblk, 0, stream>>>(
          (const u16*)Lb, nullptr, nullptr, VTb, nullptr, nullptr,
          out + xo, nullptr, nullptr, S, 2 * S, S, D, 0, 0, 0);
    }
  }
}

// Round 18
// 247.815 us; speedup vs baseline: 2.7556x; 1.0761x over previous
//
#include <hip/hip_runtime.h>
#include <math.h>

// SelfAttention B=4,S=2048,D=1024 fp32. Round 18 = r17 (266us, absmax 0.078)
// + gemmc64 (PV, VT) restructured for full-line coalesced staging:
// row-major [rows][64] bf16 LDS tiles (128B rows), lanes contiguous in k
// -> each global_load_lds wave-inst covers 8 full 128B lines (was 16 half-
// used lines). Bank conflicts on ds_read_b128 fixed via rule-#21 XOR
// swizzle: linear LDS dest + pre-swizzled global source (j^=(row&7)) +
// same XOR on read. Ledger (3 slots, lead 2, vmcnt(6)) and MFMA order
// unchanged -> bit-identical numerics. gemmf/g2/softmax verbatim r17.

typedef unsigned short u16;
typedef signed char s8;
typedef __attribute__((ext_vector_type(8))) short bf16x8;
typedef __attribute__((ext_vector_type(4))) float f32x4;
typedef __attribute__((ext_vector_type(4))) int i32x4;

__device__ __forceinline__ u16 f2bf(float x) {
  unsigned u = __float_as_uint(x);
  unsigned r = (u + 0x7fffu + ((u >> 16) & 1u)) >> 16;
  return (u16)r;
}
__device__ __forceinline__ float bf2f(u16 h) {
  return __uint_as_float((unsigned)h << 16);
}
__device__ __forceinline__ int clamp127(int q) {
  return q < -127 ? -127 : (q > 127 ? 127 : q);
}

__device__ __forceinline__ void gload_lds16(const void* g, void* l) {
  __builtin_amdgcn_global_load_lds(
      (const __attribute__((address_space(1))) unsigned int*)(g),
      (__attribute__((address_space(3))) unsigned int*)(l), 16, 0, 0);
}

template <int N>
__device__ __forceinline__ void wait_vmcnt() {
  if constexpr (N == 0) asm volatile("s_waitcnt vmcnt(0)" ::: "memory");
  else if constexpr (N == 3) asm volatile("s_waitcnt vmcnt(3)" ::: "memory");
  else if constexpr (N == 4) asm volatile("s_waitcnt vmcnt(4)" ::: "memory");
  else if constexpr (N == 6) asm volatile("s_waitcnt vmcnt(6)" ::: "memory");
}

// fp32 -> hi bf16 (+ optional lo bf16), grid-stride, vectorized
template <bool LO>
__global__ __launch_bounds__(256) void split_f32_kernel(
    const float* __restrict__ in, u16* __restrict__ hi, u16* __restrict__ lo,
    long long n) {
  long long i = ((long long)blockIdx.x * 256 + threadIdx.x) * 4;
  const long long step = (long long)gridDim.x * 256 * 4;
  for (; i < n; i += step) {
    float4 x = *(const float4*)(in + i);
    float xs[4] = {x.x, x.y, x.z, x.w};
    u16 hv[4], lv[4];
#pragma unroll
    for (int j = 0; j < 4; j++) {
      hv[j] = f2bf(xs[j]);
      if (LO) lv[j] = f2bf(xs[j] - bf2f(hv[j]));
    }
    ushort4 h;
    h.x = hv[0]; h.y = hv[1]; h.z = hv[2]; h.w = hv[3];
    *(ushort4*)(hi + i) = h;
    if (LO) {
      ushort4 l;
      l.x = lv[0]; l.y = lv[1]; l.z = lv[2]; l.w = lv[3];
      *(ushort4*)(lo + i) = l;
    }
  }
}

// Merged W conversion: z=0 Wq->(Wch,Wcl), z=1 Wk->(Wch+DD,Wcl+DD),
// z=2 Wv->Wvh (hi only). n = DD per matrix.
__global__ __launch_bounds__(256) void quantW3_kernel(
    const float* __restrict__ Wq, const float* __restrict__ Wk,
    const float* __restrict__ Wv, u16* __restrict__ Wch,
    u16* __restrict__ Wcl, u16* __restrict__ Wvh, long long n) {
  const int z = blockIdx.z;
  const float* src = (z == 0) ? Wq : ((z == 1) ? Wk : Wv);
  u16* hi = (z == 0) ? Wch : ((z == 1) ? (Wch + n) : Wvh);
  u16* lo = (z == 0) ? Wcl : ((z == 1) ? (Wcl + n) : nullptr);
  long long i = ((long long)blockIdx.x * 256 + threadIdx.x) * 4;
  const long long step = (long long)gridDim.x * 256 * 4;
  for (; i < n; i += step) {
    float4 x = *(const float4*)(src + i);
    float xs[4] = {x.x, x.y, x.z, x.w};
    u16 hv[4], lv[4];
#pragma unroll
    for (int j = 0; j < 4; j++) {
      hv[j] = f2bf(xs[j]);
      lv[j] = f2bf(xs[j] - bf2f(hv[j]));
    }
    ushort4 h;
    h.x = hv[0]; h.y = hv[1]; h.z = hv[2]; h.w = hv[3];
    *(ushort4*)(hi + i) = h;
    if (z < 2) {
      ushort4 l;
      l.x = lv[0]; l.y = lv[1]; l.z = lv[2]; l.w = lv[3];
      *(ushort4*)(lo + i) = l;
    }
  }
}

// ===== fused-split projection (r14/r16/r17-proven): [Q|K](8192x2048) i8
// 2-limb planes from (Xh+Xl) @ (Wh+Wl)^T via hh+hl+lh. BM=BN=256, BK=32,
// 512 thr = 8 waves (2M x 4N), wave tile 128x64. LDS: 2 slots x 4 planes x
// 16KB = 128KB. Lead-1: 96 MFMA/wave covers latency; vmcnt(0)+barrier/tile.
__global__ __launch_bounds__(512, 2) void gemmf(
    const u16* __restrict__ Xh, const u16* __restrict__ Xl,
    const u16* __restrict__ Wh, const u16* __restrict__ Wl,
    s8* __restrict__ Ca, s8* __restrict__ Cb) {
  constexpr int PL = 8192;         // u16 per 256x32 plane
  __shared__ u16 lds[2 * 4 * PL];  // 128 KB

  const int tid = threadIdx.x;
  const int ln = tid & 63;
  const int wid = tid >> 6;
  const int wm = wid >> 2;  // 0..1
  const int wn = wid & 3;   // 0..3
  const int m0 = blockIdx.y * 256;
  const int n0 = blockIdx.x * 256;

  f32x4 acc[8][4];
  const f32x4 zero = {0.f, 0.f, 0.f, 0.f};
#pragma unroll
  for (int i = 0; i < 8; i++)
#pragma unroll
    for (int j = 0; j < 4; j++) acc[i][j] = zero;

  auto stage = [&](int t) {
    u16* slot = lds + (t & 1) * 4 * PL;
    const int k0 = t << 5;
#pragma unroll
    for (int l = 0; l < 2; ++l) {
      const int c = tid + l * 512;
      const int row = ((c >> 6) << 4) + (c & 15);
      const int kk = ((c >> 4) & 3) * 8;
      gload_lds16(Xh + (size_t)(m0 + row) * 1024 + k0 + kk, slot + c * 8);
      gload_lds16(Xl + (size_t)(m0 + row) * 1024 + k0 + kk,
                  slot + PL + c * 8);
      gload_lds16(Wh + (size_t)(n0 + row) * 1024 + k0 + kk,
                  slot + 2 * PL + c * 8);
      gload_lds16(Wl + (size_t)(n0 + row) * 1024 + k0 + kk,
                  slot + 3 * PL + c * 8);
    }
  };

  stage(0);
  wait_vmcnt<0>();
  __builtin_amdgcn_s_barrier();
  __builtin_amdgcn_sched_barrier(0);

  for (int t = 0; t < 32; ++t) {
    if (t + 1 < 32) stage(t + 1);
    const u16* Ah = lds + (t & 1) * 4 * PL;
    const u16* Al = Ah + PL;
    const u16* Bh = Ah + 2 * PL;
    const u16* Bl = Ah + 3 * PL;
    const int fo = ln * 8;
    bf16x8 bh[4], bl[4];
#pragma unroll
    for (int j = 0; j < 4; ++j) {
      bh[j] = *(const bf16x8*)(Bh + (wn * 4 + j) * 512 + fo);
      bl[j] = *(const bf16x8*)(Bl + (wn * 4 + j) * 512 + fo);
    }
    __builtin_amdgcn_s_setprio(1);
#pragma unroll
    for (int mh = 0; mh < 2; ++mh) {
      bf16x8 ah[4], al[4];
#pragma unroll
      for (int i = 0; i < 4; ++i) {
        ah[i] = *(const bf16x8*)(Ah + (wm * 8 + mh * 4 + i) * 512 + fo);
        al[i] = *(const bf16x8*)(Al + (wm * 8 + mh * 4 + i) * 512 + fo);
      }
#pragma unroll
      for (int i = 0; i < 4; ++i)
#pragma unroll
        for (int j = 0; j < 4; ++j) {
          f32x4 v = acc[mh * 4 + i][j];
          v = __builtin_amdgcn_mfma_f32_16x16x32_bf16(ah[i], bh[j], v, 0, 0, 0);
          v = __builtin_amdgcn_mfma_f32_16x16x32_bf16(ah[i], bl[j], v, 0, 0, 0);
          v = __builtin_amdgcn_mfma_f32_16x16x32_bf16(al[i], bh[j], v, 0, 0, 0);
          acc[mh * 4 + i][j] = v;
        }
    }
    __builtin_amdgcn_s_setprio(0);
    if (t + 1 < 32) {
      wait_vmcnt<0>();
      __builtin_amdgcn_s_barrier();
      __builtin_amdgcn_sched_barrier(0);
    }
  }

  const int orow = (ln >> 4) * 4;
  const int ocol = ln & 15;
#pragma unroll
  for (int mi = 0; mi < 8; ++mi)
#pragma unroll
    for (int ni = 0; ni < 4; ++ni) {
      const int rbase = m0 + wm * 128 + mi * 16 + orow;
      const int cc = n0 + wn * 64 + ni * 16 + ocol;
#pragma unroll
      for (int i = 0; i < 4; ++i) {
        const float v = acc[mi][ni][i];
        const long long off = (long long)(rbase + i) * 2048 + cc;
        const int qa = clamp127(__float2int_rn(v * 16.f));
        const int qb = clamp127(__float2int_rn((v - qa * 0.0625f) * 2048.f));
        Ca[off] = (s8)qa;
        Cb[off] = (s8)qb;
      }
    }
}

// ===== Fused 2-limb i8 NT GEMM (QKT, r16/r17-proven).
__global__ __launch_bounds__(512, 2) void g2(
    const s8* __restrict__ Aa, const s8* __restrict__ Ab,
    const s8* __restrict__ Ba, const s8* __restrict__ Bb,
    u16* __restrict__ Ch, u16* __restrict__ Cl,
    int K, int lda, int ldb, int ldc,
    long long sA, long long sB, long long sC,
    float scaleA, float scaleC) {
  constexpr int APL = 128 * 64;
  constexpr int BPL = 256 * 64;
  constexpr int SLOT = 2 * APL + 2 * BPL;
  __shared__ s8 lds[3 * SLOT];

  const int tid = threadIdx.x;
  const int ln = tid & 63;
  const int wid = tid >> 6;
  const int wm = wid >> 2;
  const int wn = wid & 3;
  const int m0 = blockIdx.y * 128;
  const int n0 = blockIdx.x * 256;
  const int z = blockIdx.z;
  const long long za = (long long)z * sA;
  const long long zb = (long long)z * sB;

  const int NT = K >> 6;

  i32x4 accA[4][4], accC[4][4];
  const i32x4 izero = {0, 0, 0, 0};
#pragma unroll
  for (int i = 0; i < 4; i++)
#pragma unroll
    for (int j = 0; j < 4; j++) { accA[i][j] = izero; accC[i][j] = izero; }

  auto stage = [&](int t) {
    s8* slot = lds + (t % 3) * SLOT;
    const int k0 = t << 6;
    const s8* pAa = Aa + za + (size_t)m0 * lda + k0;
    const s8* pAb = Ab + za + (size_t)m0 * lda + k0;
    const s8* pBa = Ba + zb + (size_t)n0 * ldb + k0;
    const s8* pBb = Bb + zb + (size_t)n0 * ldb + k0;
    {
      const int c = tid;
      const int row = ((c >> 6) << 4) + (c & 15);
      const int kk = ((c >> 4) & 3) * 16;
      gload_lds16(pAa + (size_t)row * lda + kk, slot + c * 16);
      gload_lds16(pAb + (size_t)row * lda + kk, slot + APL + c * 16);
    }
#pragma unroll
    for (int l = 0; l < 2; ++l) {
      const int c = tid + l * 512;
      const int row = ((c >> 6) << 4) + (c & 15);
      const int kk = ((c >> 4) & 3) * 16;
      gload_lds16(pBa + (size_t)row * ldb + kk, slot + 2 * APL + c * 16);
      gload_lds16(pBb + (size_t)row * ldb + kk,
                  slot + 2 * APL + BPL + c * 16);
    }
  };

  stage(0);
  stage(1);
  wait_vmcnt<6>();
  __builtin_amdgcn_s_barrier();
  __builtin_amdgcn_sched_barrier(0);

  for (int t = 0; t < NT; ++t) {
    if (t + 2 < NT) stage(t + 2);
    const s8* Sa = lds + (t % 3) * SLOT;
    const s8* Sb = Sa + APL;
    const s8* Sba = Sa + 2 * APL;
    const s8* Sbb = Sba + BPL;
    const int fo = (ln >> 4) * 256 + (ln & 15) * 16;
    i32x4 aa[4], ab[4], ba[4], bb[4];
#pragma unroll
    for (int j = 0; j < 4; ++j) {
      ba[j] = *(const i32x4*)(Sba + (wn * 4 + j) * 1024 + fo);
      bb[j] = *(const i32x4*)(Sbb + (wn * 4 + j) * 1024 + fo);
    }
#pragma unroll
    for (int i = 0; i < 4; ++i) {
      aa[i] = *(const i32x4*)(Sa + (wm * 4 + i) * 1024 + fo);
      ab[i] = *(const i32x4*)(Sb + (wm * 4 + i) * 1024 + fo);
    }
    __builtin_amdgcn_s_setprio(1);
#pragma unroll
    for (int i = 0; i < 4; ++i)
#pragma unroll
      for (int j = 0; j < 4; ++j) {
        accA[i][j] = __builtin_amdgcn_mfma_i32_16x16x64_i8(
            aa[i], ba[j], accA[i][j], 0, 0, 0);
        accC[i][j] = __builtin_amdgcn_mfma_i32_16x16x64_i8(
            aa[i], bb[j], accC[i][j], 0, 0, 0);
        accC[i][j] = __builtin_amdgcn_mfma_i32_16x16x64_i8(
            ab[i], ba[j], accC[i][j], 0, 0, 0);
      }
    __builtin_amdgcn_s_setprio(0);
    if (t + 1 < NT) {
      if (t + 2 < NT) wait_vmcnt<6>();
      else            wait_vmcnt<0>();
      __builtin_amdgcn_s_barrier();
      __builtin_amdgcn_sched_barrier(0);
    }
  }

  const int orow = (ln >> 4) * 4;
  const int ocol = ln & 15;
#pragma unroll
  for (int mi = 0; mi < 4; ++mi)
#pragma unroll
    for (int ni = 0; ni < 4; ++ni) {
      const int rbase = m0 + wm * 64 + mi * 16 + orow;
      const int cc = n0 + wn * 64 + ni * 16 + ocol;
#pragma unroll
      for (int i = 0; i < 4; ++i) {
        const float v = (float)accA[mi][ni][i] * scaleA +
                        (float)accC[mi][ni][i] * scaleC;
        const long long off =
            (long long)(rbase + i) * ldc + cc + (long long)z * sC;
        const u16 h = f2bf(v);
        Ch[off] = h;
        Cl[off] = f2bf(v - bf2f(h));
      }
    }
}

// ===== bf16 NT GEMM BK=64, COALESCED row-major + XOR swizzle (NEW r18).
// BM=128, BN=256. LDS: A [128][64] u16 (16KB) + B [256][64] (32KB) per
// slot; 3 slots = 144KB. Row = 128B = one full HBM/L2 line; each stage
// wave-inst covers 8 whole lines (8 rows x 8 lanes contiguous).
// Swizzle (rule #21 both-sides): LDS holds elem(row, j^(row&7)) at chunk
// (row*8 + j); stage source j_g=(c&7)^(row&7); read applies same XOR ->
// ds_read_b128 2-way banked (free). Ledger: lead 2, counted vmcnt(6).
// MFMA order identical to r17 gemmc64 (a0b0 then a1b1 per k-tile).
// STORE: 0=f32 Cf, 2=bf16 Ch.
template <int STORE>
__global__ __launch_bounds__(512, 2) void gemmc64(
    const u16* __restrict__ A0, const u16* __restrict__ B0,
    float* __restrict__ Cf, u16* __restrict__ Ch,
    int K, int lda, int ldb, int ldc,
    long long sA, long long sB, long long sC) {
  constexpr int ASZ = 128 * 64;  // u16
  constexpr int BSZ = 256 * 64;  // u16
  constexpr int SLOT = ASZ + BSZ;
  __shared__ u16 lds[3 * SLOT];  // 144 KB

  const int tid = threadIdx.x;
  const int ln = tid & 63;
  const int wid = tid >> 6;
  const int wm = wid >> 2;
  const int wn = wid & 3;
  const int m0 = blockIdx.y * 128;
  const int n0 = blockIdx.x * 256;
  const int z = blockIdx.z;
  const long long za = (long long)z * sA;
  const long long zb = (long long)z * sB;

  const int NT = K >> 6;

  f32x4 acc[4][4];
  const f32x4 zero = {0.f, 0.f, 0.f, 0.f};
#pragma unroll
  for (int i = 0; i < 4; i++)
#pragma unroll
    for (int j = 0; j < 4; j++) acc[i][j] = zero;

  auto stage = [&](int t) {
    u16* slot = lds + (t % 3) * SLOT;
    const int k0 = t << 6;
    const u16* Ab = A0 + za + (size_t)m0 * lda + k0;
    const u16* Bb = B0 + zb + (size_t)n0 * ldb + k0;
#pragma unroll
    for (int l = 0; l < 2; ++l) {  // A: 1024 chunks (128 rows x 8)
      const int c = tid + l * 512;
      const int row = c >> 3;
      const int jg = (c & 7) ^ (row & 7);
      gload_lds16(Ab + (size_t)row * lda + jg * 8, slot + c * 8);
    }
#pragma unroll
    for (int l = 0; l < 4; ++l) {  // B: 2048 chunks (256 rows x 8)
      const int c = tid + l * 512;
      const int row = c >> 3;
      const int jg = (c & 7) ^ (row & 7);
      gload_lds16(Bb + (size_t)row * ldb + jg * 8, slot + ASZ + c * 8);
    }
  };

  stage(0);
  stage(1);
  wait_vmcnt<6>();
  __builtin_amdgcn_s_barrier();
  __builtin_amdgcn_sched_barrier(0);

  const int r15 = ln & 15;
  const int jk = ln >> 4;                       // 0..3 (k-chunk in half)
  const int sw0 = ((jk ^ (r15 & 7)) * 8);       // k-half 0
  const int sw1 = (((4 + jk) ^ (r15 & 7)) * 8); // k-half 1

  for (int t = 0; t < NT; ++t) {
    if (t + 2 < NT) stage(t + 2);
    const u16* Abuf = lds + (t % 3) * SLOT;
    const u16* Bbuf = Abuf + ASZ;
    bf16x8 a0[4], a1[4], b0[4], b1[4];
#pragma unroll
    for (int j = 0; j < 4; ++j) {
      const int rb = ((wn * 4 + j) * 16 + r15) * 64;
      b0[j] = *(const bf16x8*)(Bbuf + rb + sw0);
      b1[j] = *(const bf16x8*)(Bbuf + rb + sw1);
    }
#pragma unroll
    for (int i = 0; i < 4; ++i) {
      const int ra = ((wm * 4 + i) * 16 + r15) * 64;
      a0[i] = *(const bf16x8*)(Abuf + ra + sw0);
      a1[i] = *(const bf16x8*)(Abuf + ra + sw1);
    }
    __builtin_amdgcn_s_setprio(1);
#pragma unroll
    for (int i = 0; i < 4; ++i)
#pragma unroll
      for (int j = 0; j < 4; ++j) {
        acc[i][j] = __builtin_amdgcn_mfma_f32_16x16x32_bf16(
            a0[i], b0[j], acc[i][j], 0, 0, 0);
        acc[i][j] = __builtin_amdgcn_mfma_f32_16x16x32_bf16(
            a1[i], b1[j], acc[i][j], 0, 0, 0);
      }
    __builtin_amdgcn_s_setprio(0);
    if (t + 1 < NT) {
      if (t + 2 < NT) wait_vmcnt<6>();
      else            wait_vmcnt<0>();
      __builtin_amdgcn_s_barrier();
      __builtin_amdgcn_sched_barrier(0);
    }
  }

  const int orow = (ln >> 4) * 4;
  const int ocol = ln & 15;
#pragma unroll
  for (int mi = 0; mi < 4; ++mi)
#pragma unroll
    for (int ni = 0; ni < 4; ++ni) {
      const int rbase = m0 + wm * 64 + mi * 16 + orow;
      const int cc = n0 + wn * 64 + ni * 16 + ocol;
#pragma unroll
      for (int i = 0; i < 4; ++i) {
        const float v = acc[mi][ni][i];
        const long long off =
            (long long)(rbase + i) * ldc + cc + (long long)z * sC;
        if (STORE == 0) Cf[off] = v;
        else            Ch[off] = f2bf(v);
      }
    }
}

// ===== bf16 GEMM BK=32 (r9-proven) — low tier only.
template <int NSEG, int STORE, int M_REP>
__global__ __launch_bounds__(512, 2) void gemmc(
    const u16* __restrict__ A0, const u16* __restrict__ A1,
    const u16* __restrict__ A2, const u16* __restrict__ B0,
    const u16* __restrict__ B1, const u16* __restrict__ B2,
    float* __restrict__ Cf, u16* __restrict__ Ch, u16* __restrict__ Cl,
    int Kseg, int lda, int ldb, int ldc,
    long long sA, long long sB, long long sC) {
  constexpr int BM = 32 * M_REP;
  constexpr int ASZ = BM * 32;
  constexpr int BSZ = 8192;
  constexpr int SLOT = ASZ + BSZ;
  constexpr int LA = M_REP / 4;
  constexpr int L = LA + 2;
  __shared__ u16 lds[3 * SLOT];

  const int tid = threadIdx.x;
  const int ln = tid & 63;
  const int wid = tid >> 6;
  const int wm = wid >> 2;
  const int wn = wid & 3;
  const int m0 = blockIdx.y * BM;
  const int n0 = blockIdx.x * 256;
  const int z = blockIdx.z;
  const long long za = (long long)z * sA;
  const long long zb = (long long)z * sB;

  const int NT = NSEG * (Kseg >> 5);

  f32x4 acc[M_REP][4];
  const f32x4 zero = {0.f, 0.f, 0.f, 0.f};
#pragma unroll
  for (int i = 0; i < M_REP; i++)
#pragma unroll
    for (int j = 0; j < 4; j++) acc[i][j] = zero;

  auto baseA = [&](int t) -> const u16* {
    int kk = t << 5;
    const u16* p = A0;
    if (NSEG >= 2 && kk >= Kseg) { kk -= Kseg; p = A1; }
    if (NSEG >= 3 && kk >= Kseg) { kk -= Kseg; p = A2; }
    return p + za + (size_t)m0 * lda + kk;
  };
  auto baseB = [&](int t) -> const u16* {
    int kk = t << 5;
    const u16* p = B0;
    if (NSEG >= 2 && kk >= Kseg) { kk -= Kseg; p = B1; }
    if (NSEG >= 3 && kk >= Kseg) { kk -= Kseg; p = B2; }
    return p + zb + (size_t)n0 * ldb + kk;
  };
  auto stage = [&](int t) {
    u16* slot = lds + (t % 3) * SLOT;
    const u16* Ab = baseA(t);
    const u16* Bb = baseB(t);
#pragma unroll
    for (int l = 0; l < LA; ++l) {
      const int c = tid + l * 512;
      const int row = ((c >> 6) << 4) + (c & 15);
      const int kk = ((c >> 4) & 3) * 8;
      gload_lds16(Ab + (size_t)row * lda + kk, slot + c * 8);
    }
#pragma unroll
    for (int l = 0; l < 2; ++l) {
      const int c = tid + l * 512;
      const int row = ((c >> 6) << 4) + (c & 15);
      const int kk = ((c >> 4) & 3) * 8;
      gload_lds16(Bb + (size_t)row * ldb + kk, slot + ASZ + c * 8);
    }
  };

  stage(0);
  stage(1);
  wait_vmcnt<L>();
  __builtin_amdgcn_s_barrier();
  __builtin_amdgcn_sched_barrier(0);

  for (int t = 0; t < NT; ++t) {
    if (t + 2 < NT) stage(t + 2);
    const u16* Abuf = lds + (t % 3) * SLOT;
    const u16* Bbuf = Abuf + ASZ;
    const int fo = ln * 8;
    bf16x8 a[M_REP], b[4];
#pragma unroll
    for (int j = 0; j < 4; ++j)
      b[j] = *(const bf16x8*)(Bbuf + (wn * 4 + j) * 512 + fo);
#pragma unroll
    for (int i = 0; i < M_REP; ++i)
      a[i] = *(const bf16x8*)(Abuf + (wm * M_REP + i) * 512 + fo);
    __builtin_amdgcn_s_setprio(1);
#pragma unroll
    for (int i = 0; i < M_REP; ++i)
#pragma unroll
      for (int j = 0; j < 4; ++j)
        acc[i][j] = __builtin_amdgcn_mfma_f32_16x16x32_bf16(
            a[i], b[j], acc[i][j], 0, 0, 0);
    __builtin_amdgcn_s_setprio(0);
    if (t + 1 < NT) {
      if (t + 2 < NT) wait_vmcnt<L>();
      else            wait_vmcnt<0>();
      __builtin_amdgcn_s_barrier();
      __builtin_amdgcn_sched_barrier(0);
    }
  }

  const int orow = (ln >> 4) * 4;
  const int ocol = ln & 15;
#pragma unroll
  for (int mi = 0; mi < M_REP; ++mi)
#pragma unroll
    for (int ni = 0; ni < 4; ++ni) {
      const int rbase = m0 + wm * (M_REP * 16) + mi * 16 + orow;
      const int cc = n0 + wn * 64 + ni * 16 + ocol;
#pragma unroll
      for (int i = 0; i < 4; ++i) {
        const float v = acc[mi][ni][i];
        const long long off =
            (long long)(rbase + i) * ldc + cc + (long long)z * sC;
        if (STORE == 0) {
          Cf[off] = v;
        } else if (STORE == 1) {
          const u16 h = f2bf(v);
          Ch[off] = h;
          Cl[off] = f2bf(v - bf2f(h));
        } else {
          Ch[off] = f2bf(v);
        }
      }
    }
}

// ---- softmax (row = 2048) ----
__device__ __forceinline__ float blk_max(float v, float* red) {
  const int wv = threadIdx.x >> 6, lnn = threadIdx.x & 63;
#pragma unroll
  for (int off = 32; off; off >>= 1) v = fmaxf(v, __shfl_xor(v, off));
  if (lnn == 0) red[wv] = v;
  __syncthreads();
  return fmaxf(fmaxf(red[0], red[1]), fmaxf(red[2], red[3]));
}
__device__ __forceinline__ float blk_sum(float v, float* red) {
  const int wv = threadIdx.x >> 6, lnn = threadIdx.x & 63;
#pragma unroll
  for (int off = 32; off; off >>= 1) v += __shfl_xor(v, off);
  if (lnn == 0) red[wv] = v;
  __syncthreads();
  return red[0] + red[1] + red[2] + red[3];
}

// f32 L row -> bf16 P in place (row stride stays 4096 u16) [low tier]
__global__ __launch_bounds__(256) void softmax_inplace(float* __restrict__ L) {
  float* p = L + (size_t)blockIdx.x * 2048;
  const int t = threadIdx.x;
  __shared__ float redm[4];
  __shared__ float reds[4];
  float4 x0 = *(const float4*)(p + t * 4);
  float4 x1 = *(const float4*)(p + 1024 + t * 4);
  float m = fmaxf(fmaxf(fmaxf(x0.x, x0.y), fmaxf(x0.z, x0.w)),
                  fmaxf(fmaxf(x1.x, x1.y), fmaxf(x1.z, x1.w)));
  m = blk_max(m, redm);
  float e[8];
  e[0] = __expf(x0.x - m); e[1] = __expf(x0.y - m);
  e[2] = __expf(x0.z - m); e[3] = __expf(x0.w - m);
  e[4] = __expf(x1.x - m); e[5] = __expf(x1.y - m);
  e[6] = __expf(x1.z - m); e[7] = __expf(x1.w - m);
  float s = e[0] + e[1] + e[2] + e[3] + e[4] + e[5] + e[6] + e[7];
  s = blk_sum(s, reds);
  const float inv = 1.f / s;
  u16* q = (u16*)p;
  ushort4 o0, o1;
  o0.x = f2bf(e[0] * inv); o0.y = f2bf(e[1] * inv);
  o0.z = f2bf(e[2] * inv); o0.w = f2bf(e[3] * inv);
  o1.x = f2bf(e[4] * inv); o1.y = f2bf(e[5] * inv);
  o1.z = f2bf(e[6] * inv); o1.w = f2bf(e[7] * inv);
  *(ushort4*)(q + t * 4) = o0;
  *(ushort4*)(q + 1024 + t * 4) = o1;
}

// split-bf16 L (Lh+Ll) -> bf16 P over Lh row (stride 2048 u16)
__global__ __launch_bounds__(256) void softmax_split(
    u16* __restrict__ Lh, const u16* __restrict__ Ll) {
  u16* ph = Lh + (size_t)blockIdx.x * 2048;
  const u16* pl = Ll + (size_t)blockIdx.x * 2048;
  const int t = threadIdx.x;
  __shared__ float redm[4];
  __shared__ float reds[4];
  ushort4 h0 = *(const ushort4*)(ph + t * 4);
  ushort4 h1 = *(const ushort4*)(ph + 1024 + t * 4);
  ushort4 l0 = *(const ushort4*)(pl + t * 4);
  ushort4 l1 = *(const ushort4*)(pl + 1024 + t * 4);
  float x[8];
  x[0] = bf2f(h0.x) + bf2f(l0.x); x[1] = bf2f(h0.y) + bf2f(l0.y);
  x[2] = bf2f(h0.z) + bf2f(l0.z); x[3] = bf2f(h0.w) + bf2f(l0.w);
  x[4] = bf2f(h1.x) + bf2f(l1.x); x[5] = bf2f(h1.y) + bf2f(l1.y);
  x[6] = bf2f(h1.z) + bf2f(l1.z); x[7] = bf2f(h1.w) + bf2f(l1.w);
  float m = fmaxf(fmaxf(fmaxf(x[0], x[1]), fmaxf(x[2], x[3])),
                  fmaxf(fmaxf(x[4], x[5]), fmaxf(x[6], x[7])));
  m = blk_max(m, redm);
  float e[8];
#pragma unroll
  for (int j = 0; j < 8; ++j) e[j] = __expf(x[j] - m);
  float s = e[0] + e[1] + e[2] + e[3] + e[4] + e[5] + e[6] + e[7];
  s = blk_sum(s, reds);
  const float inv = 1.f / s;
  ushort4 o0, o1;
  o0.x = f2bf(e[0] * inv); o0.y = f2bf(e[1] * inv);
  o0.z = f2bf(e[2] * inv); o0.w = f2bf(e[3] * inv);
  o1.x = f2bf(e[4] * inv); o1.y = f2bf(e[5] * inv);
  o1.z = f2bf(e[6] * inv); o1.w = f2bf(e[7] * inv);
  *(ushort4*)(ph + t * 4) = o0;
  *(ushort4*)(ph + 1024 + t * 4) = o1;
}

extern "C" void kernel_launch(void* const* d_in, const int* in_sizes, int n_in,
                              void* d_out, int out_size, void* d_ws, size_t ws_size,
                              hipStream_t stream) {
  constexpr int Bn = 4, S = 2048, D = 1024;
  constexpr long long TOK = (long long)Bn * S;  // 8192
  constexpr long long DD = (long long)D * D;
  const float* X = (const float*)d_in[0];
  const float* Wq = (const float*)d_in[1];
  const float* Wk = (const float*)d_in[2];
  const float* Wv = (const float*)d_in[3];
  float* out = (float*)d_out;
  const dim3 blk(256);
  const dim3 gblk(512);

  char* w = (char*)d_ws;
  auto au16 = [&](long long n) { u16* p = (u16*)w; w += n * 2; return p; };
  auto as8 = [&](long long n) { s8* p = (s8*)w; w += n; return p; };

  if (ws_size >= (size_t)127926272ULL) {
    // Layout (127.93 MB): Xh Xl | Wch Wcl Wvh | QKa QKb (i8) | VT | Ll
    u16* Xh = au16(TOK * D);          // dead after VT -> hosts Lh
    u16* Xl = au16(TOK * D);
    u16* Wch = au16(2 * DD);
    u16* Wcl = au16(2 * DD);
    u16* Wvh = au16(DD);
    s8* QKa = as8(TOK * 2 * D);       // i8 hi plane, cols 0..1023=Q, rest=K
    s8* QKb = as8(TOK * 2 * D);       // i8 lo plane
    u16* VT = au16((long long)D * TOK);  // [1024][8192]
    u16* Ll = au16(TOK * S);          // logit lo plane (tail)
    u16* Lh = (u16*)d_ws;             // logit hi plane over dead X region

    split_f32_kernel<true><<<2048, blk, 0, stream>>>(X, Xh, Xl, TOK * D);
    quantW3_kernel<<<dim3(256, 1, 3), blk, 0, stream>>>(
        Wq, Wk, Wv, Wch, Wcl, Wvh, DD);

    // fused-split Q|K projection -> i8 planes: (8,32) = 256 blocks
    gemmf<<<dim3(8, 32, 1), gblk, 0, stream>>>(
        Xh, Xl, Wch, Wcl, QKa, QKb);
    // VT[e,tok] = Wvh . Xh^T : coalesced BK=64, (32,8) = 256 blocks
    gemmc64<2><<<dim3(32, 8, 1), gblk, 0, stream>>>(
        Wvh, Xh, nullptr, VT, D, D, D, (int)TOK, 0, 0, 0);
    // X region dead now.

    // QKT fused-i8, one z=4 launch: (8,16,4) = 512 blocks
    g2<<<dim3(8, 16, 4), gblk, 0, stream>>>(
        QKa, QKb, QKa + D, QKb + D, Lh, Ll,
        D, 2 * D, 2 * D, S,
        (long long)S * 2 * D, (long long)S * 2 * D, (long long)S * S,
        3.90625e-3f, 3.0517578125e-5f);
    softmax_split<<<dim3(4 * S), blk, 0, stream>>>(Lh, Ll);
    // O = P . VT^T : coalesced BK=64, (4,16,4) = 256 blocks
    gemmc64<0><<<dim3(4, 16, 4), gblk, 0, stream>>>(
        Lh, VT, out, nullptr, S, S, (int)TOK, D,
        (long long)S * S, (long long)S, (long long)S * D);
  } else {
    // Low tier (~82 MB): per-batch bf16 path (r9/r16)
    u16* Xh = au16(TOK * D);
    u16* Xl = au16(TOK * D);
    u16* Wch = au16(2 * DD);
    u16* Wcl = au16(2 * DD);
    u16* Wvh = au16(DD);
    u16* QKhb = au16((long long)S * 2 * D);
    u16* QKlb = au16((long long)S * 2 * D);
    u16* VTb = au16((long long)D * S);
    float* Lb = (float*)w;

    split_f32_kernel<true><<<2048, blk, 0, stream>>>(X, Xh, Xl, TOK * D);
    split_f32_kernel<true><<<512, blk, 0, stream>>>(Wq, Wch, Wcl, DD);
    split_f32_kernel<true><<<512, blk, 0, stream>>>(Wk, Wch + DD, Wcl + DD, DD);
    split_f32_kernel<false><<<512, blk, 0, stream>>>(Wv, Wvh, nullptr, DD);

    for (int b = 0; b < Bn; ++b) {
      const long long xo = (long long)b * S * D;
      gemmc<3, 1, 8><<<dim3(8, 8, 1), gblk, 0, stream>>>(
          Xh + xo, Xh + xo, Xl + xo, Wch, Wcl, Wch, nullptr, QKhb, QKlb,
          D, D, D, 2 * D, 0, 0, 0);
      gemmc<1, 2, 4><<<dim3(8, 8, 1), gblk, 0, stream>>>(
          Wvh, nullptr, nullptr, Xh + xo, nullptr, nullptr, nullptr, VTb,
          nullptr, D, D, D, S, 0, 0, 0);
      gemmc<3, 0, 4><<<dim3(8, 16, 1), gblk, 0, stream>>>(
          QKhb, QKhb, QKlb, QKhb + D, QKlb + D, QKhb + D,
          Lb, nullptr, nullptr, D, 2 * D, 2 * D, S, 0, 0, 0);
      softmax_inplace<<<dim3(S), blk, 0, stream>>>(Lb);
      gemmc<1, 0, 4><<<dim3(4, 16, 1), gblk, 0, stream>>>(
          (const u16*)Lb, nullptr, nullptr, VTb, nullptr, nullptr,
          out + xo, nullptr, nullptr, S, 2 * S, S, D, 0, 0, 0);
    }
  }
}

// Round 19
// 243.834 us; speedup vs baseline: 2.8005x; 1.0163x over previous
//
#include <hip/hip_runtime.h>
#include <math.h>

// SelfAttention B=4,S=2048,D=1024 fp32. Round 19 = r18 (247.8us, absmax
// 0.078) + QKT switched to g2p: fused 2-limb i8 GEMM with FULL-LINE staging
// (r18 pattern: row-major [rows][128B] planes, chunk c -> row=c>>3,
// j8=(c&7)^(row&7); 8 rows x whole lines per wave-inst; XOR -> 2-way banks).
// BM=BN=128, slot=BK128 (2 k-steps), 2 slots (128KB), lead-1 vmcnt(0)
// ledger (gemmf-proven). i32 accumulation associative -> numerics identical.
// gemmf / gemmc64 / softmax / low tier verbatim r18.

typedef unsigned short u16;
typedef signed char s8;
typedef __attribute__((ext_vector_type(8))) short bf16x8;
typedef __attribute__((ext_vector_type(4))) float f32x4;
typedef __attribute__((ext_vector_type(4))) int i32x4;

__device__ __forceinline__ u16 f2bf(float x) {
  unsigned u = __float_as_uint(x);
  unsigned r = (u + 0x7fffu + ((u >> 16) & 1u)) >> 16;
  return (u16)r;
}
__device__ __forceinline__ float bf2f(u16 h) {
  return __uint_as_float((unsigned)h << 16);
}
__device__ __forceinline__ int clamp127(int q) {
  return q < -127 ? -127 : (q > 127 ? 127 : q);
}

__device__ __forceinline__ void gload_lds16(const void* g, void* l) {
  __builtin_amdgcn_global_load_lds(
      (const __attribute__((address_space(1))) unsigned int*)(g),
      (__attribute__((address_space(3))) unsigned int*)(l), 16, 0, 0);
}

template <int N>
__device__ __forceinline__ void wait_vmcnt() {
  if constexpr (N == 0) asm volatile("s_waitcnt vmcnt(0)" ::: "memory");
  else if constexpr (N == 4) asm volatile("s_waitcnt vmcnt(4)" ::: "memory");
  else if constexpr (N == 6) asm volatile("s_waitcnt vmcnt(6)" ::: "memory");
}

// fp32 -> hi bf16 (+ optional lo bf16), grid-stride, vectorized
template <bool LO>
__global__ __launch_bounds__(256) void split_f32_kernel(
    const float* __restrict__ in, u16* __restrict__ hi, u16* __restrict__ lo,
    long long n) {
  long long i = ((long long)blockIdx.x * 256 + threadIdx.x) * 4;
  const long long step = (long long)gridDim.x * 256 * 4;
  for (; i < n; i += step) {
    float4 x = *(const float4*)(in + i);
    float xs[4] = {x.x, x.y, x.z, x.w};
    u16 hv[4], lv[4];
#pragma unroll
    for (int j = 0; j < 4; j++) {
      hv[j] = f2bf(xs[j]);
      if (LO) lv[j] = f2bf(xs[j] - bf2f(hv[j]));
    }
    ushort4 h;
    h.x = hv[0]; h.y = hv[1]; h.z = hv[2]; h.w = hv[3];
    *(ushort4*)(hi + i) = h;
    if (LO) {
      ushort4 l;
      l.x = lv[0]; l.y = lv[1]; l.z = lv[2]; l.w = lv[3];
      *(ushort4*)(lo + i) = l;
    }
  }
}

// Merged W conversion: z=0 Wq->(Wch,Wcl), z=1 Wk->(Wch+DD,Wcl+DD),
// z=2 Wv->Wvh (hi only). n = DD per matrix.
__global__ __launch_bounds__(256) void quantW3_kernel(
    const float* __restrict__ Wq, const float* __restrict__ Wk,
    const float* __restrict__ Wv, u16* __restrict__ Wch,
    u16* __restrict__ Wcl, u16* __restrict__ Wvh, long long n) {
  const int z = blockIdx.z;
  const float* src = (z == 0) ? Wq : ((z == 1) ? Wk : Wv);
  u16* hi = (z == 0) ? Wch : ((z == 1) ? (Wch + n) : Wvh);
  u16* lo = (z == 0) ? Wcl : ((z == 1) ? (Wcl + n) : nullptr);
  long long i = ((long long)blockIdx.x * 256 + threadIdx.x) * 4;
  const long long step = (long long)gridDim.x * 256 * 4;
  for (; i < n; i += step) {
    float4 x = *(const float4*)(src + i);
    float xs[4] = {x.x, x.y, x.z, x.w};
    u16 hv[4], lv[4];
#pragma unroll
    for (int j = 0; j < 4; j++) {
      hv[j] = f2bf(xs[j]);
      lv[j] = f2bf(xs[j] - bf2f(hv[j]));
    }
    ushort4 h;
    h.x = hv[0]; h.y = hv[1]; h.z = hv[2]; h.w = hv[3];
    *(ushort4*)(hi + i) = h;
    if (z < 2) {
      ushort4 l;
      l.x = lv[0]; l.y = lv[1]; l.z = lv[2]; l.w = lv[3];
      *(ushort4*)(lo + i) = l;
    }
  }
}

// ===== fused-split projection (r14-r18 proven): [Q|K](8192x2048) i8 2-limb
// planes from (Xh+Xl) @ (Wh+Wl)^T via hh+hl+lh. BM=BN=256, BK=32, 512 thr
// = 8 waves (2M x 4N), wave tile 128x64. LDS: 2 slots x 4 planes x 16KB =
// 128KB. Lead-1: 96 MFMA/wave covers latency; vmcnt(0)+barrier per tile.
__global__ __launch_bounds__(512, 2) void gemmf(
    const u16* __restrict__ Xh, const u16* __restrict__ Xl,
    const u16* __restrict__ Wh, const u16* __restrict__ Wl,
    s8* __restrict__ Ca, s8* __restrict__ Cb) {
  constexpr int PL = 8192;         // u16 per 256x32 plane
  __shared__ u16 lds[2 * 4 * PL];  // 128 KB

  const int tid = threadIdx.x;
  const int ln = tid & 63;
  const int wid = tid >> 6;
  const int wm = wid >> 2;  // 0..1
  const int wn = wid & 3;   // 0..3
  const int m0 = blockIdx.y * 256;
  const int n0 = blockIdx.x * 256;

  f32x4 acc[8][4];
  const f32x4 zero = {0.f, 0.f, 0.f, 0.f};
#pragma unroll
  for (int i = 0; i < 8; i++)
#pragma unroll
    for (int j = 0; j < 4; j++) acc[i][j] = zero;

  auto stage = [&](int t) {
    u16* slot = lds + (t & 1) * 4 * PL;
    const int k0 = t << 5;
#pragma unroll
    for (int l = 0; l < 2; ++l) {
      const int c = tid + l * 512;
      const int row = ((c >> 6) << 4) + (c & 15);
      const int kk = ((c >> 4) & 3) * 8;
      gload_lds16(Xh + (size_t)(m0 + row) * 1024 + k0 + kk, slot + c * 8);
      gload_lds16(Xl + (size_t)(m0 + row) * 1024 + k0 + kk,
                  slot + PL + c * 8);
      gload_lds16(Wh + (size_t)(n0 + row) * 1024 + k0 + kk,
                  slot + 2 * PL + c * 8);
      gload_lds16(Wl + (size_t)(n0 + row) * 1024 + k0 + kk,
                  slot + 3 * PL + c * 8);
    }
  };

  stage(0);
  wait_vmcnt<0>();
  __builtin_amdgcn_s_barrier();
  __builtin_amdgcn_sched_barrier(0);

  for (int t = 0; t < 32; ++t) {
    if (t + 1 < 32) stage(t + 1);
    const u16* Ah = lds + (t & 1) * 4 * PL;
    const u16* Al = Ah + PL;
    const u16* Bh = Ah + 2 * PL;
    const u16* Bl = Ah + 3 * PL;
    const int fo = ln * 8;
    bf16x8 bh[4], bl[4];
#pragma unroll
    for (int j = 0; j < 4; ++j) {
      bh[j] = *(const bf16x8*)(Bh + (wn * 4 + j) * 512 + fo);
      bl[j] = *(const bf16x8*)(Bl + (wn * 4 + j) * 512 + fo);
    }
    __builtin_amdgcn_s_setprio(1);
#pragma unroll
    for (int mh = 0; mh < 2; ++mh) {
      bf16x8 ah[4], al[4];
#pragma unroll
      for (int i = 0; i < 4; ++i) {
        ah[i] = *(const bf16x8*)(Ah + (wm * 8 + mh * 4 + i) * 512 + fo);
        al[i] = *(const bf16x8*)(Al + (wm * 8 + mh * 4 + i) * 512 + fo);
      }
#pragma unroll
      for (int i = 0; i < 4; ++i)
#pragma unroll
        for (int j = 0; j < 4; ++j) {
          f32x4 v = acc[mh * 4 + i][j];
          v = __builtin_amdgcn_mfma_f32_16x16x32_bf16(ah[i], bh[j], v, 0, 0, 0);
          v = __builtin_amdgcn_mfma_f32_16x16x32_bf16(ah[i], bl[j], v, 0, 0, 0);
          v = __builtin_amdgcn_mfma_f32_16x16x32_bf16(al[i], bh[j], v, 0, 0, 0);
          acc[mh * 4 + i][j] = v;
        }
    }
    __builtin_amdgcn_s_setprio(0);
    if (t + 1 < 32) {
      wait_vmcnt<0>();
      __builtin_amdgcn_s_barrier();
      __builtin_amdgcn_sched_barrier(0);
    }
  }

  const int orow = (ln >> 4) * 4;
  const int ocol = ln & 15;
#pragma unroll
  for (int mi = 0; mi < 8; ++mi)
#pragma unroll
    for (int ni = 0; ni < 4; ++ni) {
      const int rbase = m0 + wm * 128 + mi * 16 + orow;
      const int cc = n0 + wn * 64 + ni * 16 + ocol;
#pragma unroll
      for (int i = 0; i < 4; ++i) {
        const float v = acc[mi][ni][i];
        const long long off = (long long)(rbase + i) * 2048 + cc;
        const int qa = clamp127(__float2int_rn(v * 16.f));
        const int qb = clamp127(__float2int_rn((v - qa * 0.0625f) * 2048.f));
        Ca[off] = (s8)qa;
        Cb[off] = (s8)qb;
      }
    }
}

// ===== g2p (NEW r19): fused 2-limb i8 NT GEMM, FULL-LINE staging.
// C = (Aa+Ab/128).(Ba+Bb/128)^T, accA = Aa.Ba, accC = Aa.Bb + Ab.Ba,
// v = accA*scaleA + accC*scaleC. BM=BN=128; slot covers BK=128 (2 k-steps
// of the 16x16x64 i8 MFMA). LDS: 2 slots x [Aa|Ab|Ba|Bb] 16KB planes =
// 128KB. Staging (r18-validated pattern): plane = [128 rows][128 B];
// chunk c -> row=c>>3, j8=(c&7)^(row&7); dest=c*16 linear; wave-inst = 8
// rows x full 128B lines. Read: global k-chunk g at row*128+(g^(row&7))*16
// -> 2-way banks (free). Lead-1 ledger (gemmf-proven): stage(t+1) at top,
// vmcnt(0)+barrier at end. 8 waves (2M x 4N), wave tile 64x32.
__global__ __launch_bounds__(512, 2) void g2p(
    const s8* __restrict__ Aa, const s8* __restrict__ Ab,
    const s8* __restrict__ Ba, const s8* __restrict__ Bb,
    u16* __restrict__ Ch, u16* __restrict__ Cl,
    int K, int lda, int ldb, int ldc,
    long long sA, long long sB, long long sC,
    float scaleA, float scaleC) {
  constexpr int PL = 128 * 128;   // 16 KB per plane
  __shared__ s8 lds[2 * 4 * PL];  // 128 KB

  const int tid = threadIdx.x;
  const int ln = tid & 63;
  const int wid = tid >> 6;
  const int wm = wid >> 2;  // 0..1 (M half)
  const int wn = wid & 3;   // 0..3 (N quarter)
  const int m0 = blockIdx.y * 128;
  const int n0 = blockIdx.x * 128;
  const int z = blockIdx.z;
  const long long za = (long long)z * sA;
  const long long zb = (long long)z * sB;

  const int NT = K >> 7;  // slots of BK=128

  i32x4 accA[4][2], accC[4][2];
  const i32x4 izero = {0, 0, 0, 0};
#pragma unroll
  for (int i = 0; i < 4; i++)
#pragma unroll
    for (int j = 0; j < 2; j++) { accA[i][j] = izero; accC[i][j] = izero; }

  auto stage = [&](int t) {
    s8* slot = lds + (t & 1) * 4 * PL;
    const int k0 = t << 7;
    const s8* pAa = Aa + za + (size_t)m0 * lda + k0;
    const s8* pAb = Ab + za + (size_t)m0 * lda + k0;
    const s8* pBa = Ba + zb + (size_t)n0 * ldb + k0;
    const s8* pBb = Bb + zb + (size_t)n0 * ldb + k0;
#pragma unroll
    for (int l = 0; l < 2; ++l) {
      const int c = tid + l * 512;
      const int row = c >> 3;
      const int j8 = (c & 7) ^ (row & 7);
      gload_lds16(pAa + (size_t)row * lda + j8 * 16, slot + c * 16);
      gload_lds16(pAb + (size_t)row * lda + j8 * 16, slot + PL + c * 16);
      gload_lds16(pBa + (size_t)row * ldb + j8 * 16, slot + 2 * PL + c * 16);
      gload_lds16(pBb + (size_t)row * ldb + j8 * 16, slot + 3 * PL + c * 16);
    }
  };

  stage(0);
  wait_vmcnt<0>();
  __builtin_amdgcn_s_barrier();
  __builtin_amdgcn_sched_barrier(0);

  const int r15 = ln & 15;
  const int jk = ln >> 4;  // 0..3: k-chunk within 64-byte k-step

  for (int t = 0; t < NT; ++t) {
    if (t + 1 < NT) stage(t + 1);
    const s8* base = lds + (t & 1) * 4 * PL;
#pragma unroll
    for (int ks = 0; ks < 2; ++ks) {
      i32x4 aa[4], ab[4], ba[2], bb[2];
#pragma unroll
      for (int j = 0; j < 2; ++j) {
        const int row = wn * 32 + j * 16 + r15;
        const int off = row * 128 + (((ks * 4 + jk) ^ (row & 7)) * 16);
        ba[j] = *(const i32x4*)(base + 2 * PL + off);
        bb[j] = *(const i32x4*)(base + 3 * PL + off);
      }
#pragma unroll
      for (int i = 0; i < 4; ++i) {
        const int row = wm * 64 + i * 16 + r15;
        const int off = row * 128 + (((ks * 4 + jk) ^ (row & 7)) * 16);
        aa[i] = *(const i32x4*)(base + off);
        ab[i] = *(const i32x4*)(base + PL + off);
      }
      __builtin_amdgcn_s_setprio(1);
#pragma unroll
      for (int i = 0; i < 4; ++i)
#pragma unroll
        for (int j = 0; j < 2; ++j) {
          accA[i][j] = __builtin_amdgcn_mfma_i32_16x16x64_i8(
              aa[i], ba[j], accA[i][j], 0, 0, 0);
          accC[i][j] = __builtin_amdgcn_mfma_i32_16x16x64_i8(
              aa[i], bb[j], accC[i][j], 0, 0, 0);
          accC[i][j] = __builtin_amdgcn_mfma_i32_16x16x64_i8(
              ab[i], ba[j], accC[i][j], 0, 0, 0);
        }
      __builtin_amdgcn_s_setprio(0);
    }
    if (t + 1 < NT) {
      wait_vmcnt<0>();
      __builtin_amdgcn_s_barrier();
      __builtin_amdgcn_sched_barrier(0);
    }
  }

  // epilogue: C/D layout col=lane&15, row=(lane>>4)*4+reg (validated)
  const int orow = (ln >> 4) * 4;
  const int ocol = ln & 15;
#pragma unroll
  for (int mi = 0; mi < 4; ++mi)
#pragma unroll
    for (int ni = 0; ni < 2; ++ni) {
      const int rbase = m0 + wm * 64 + mi * 16 + orow;
      const int cc = n0 + wn * 32 + ni * 16 + ocol;
#pragma unroll
      for (int i = 0; i < 4; ++i) {
        const float v = (float)accA[mi][ni][i] * scaleA +
                        (float)accC[mi][ni][i] * scaleC;
        const long long off =
            (long long)(rbase + i) * ldc + cc + (long long)z * sC;
        const u16 h = f2bf(v);
        Ch[off] = h;
        Cl[off] = f2bf(v - bf2f(h));
      }
    }
}

// ===== bf16 NT GEMM BK=64, coalesced row-major + XOR swizzle (r18-proven).
// BM=128, BN=256. LDS 3 slots x 48KB. Lead 2, counted vmcnt(6).
// STORE: 0=f32 Cf, 2=bf16 Ch.
template <int STORE>
__global__ __launch_bounds__(512, 2) void gemmc64(
    const u16* __restrict__ A0, const u16* __restrict__ B0,
    float* __restrict__ Cf, u16* __restrict__ Ch,
    int K, int lda, int ldb, int ldc,
    long long sA, long long sB, long long sC) {
  constexpr int ASZ = 128 * 64;  // u16
  constexpr int BSZ = 256 * 64;  // u16
  constexpr int SLOT = ASZ + BSZ;
  __shared__ u16 lds[3 * SLOT];  // 144 KB

  const int tid = threadIdx.x;
  const int ln = tid & 63;
  const int wid = tid >> 6;
  const int wm = wid >> 2;
  const int wn = wid & 3;
  const int m0 = blockIdx.y * 128;
  const int n0 = blockIdx.x * 256;
  const int z = blockIdx.z;
  const long long za = (long long)z * sA;
  const long long zb = (long long)z * sB;

  const int NT = K >> 6;

  f32x4 acc[4][4];
  const f32x4 zero = {0.f, 0.f, 0.f, 0.f};
#pragma unroll
  for (int i = 0; i < 4; i++)
#pragma unroll
    for (int j = 0; j < 4; j++) acc[i][j] = zero;

  auto stage = [&](int t) {
    u16* slot = lds + (t % 3) * SLOT;
    const int k0 = t << 6;
    const u16* Ab = A0 + za + (size_t)m0 * lda + k0;
    const u16* Bb = B0 + zb + (size_t)n0 * ldb + k0;
#pragma unroll
    for (int l = 0; l < 2; ++l) {
      const int c = tid + l * 512;
      const int row = c >> 3;
      const int jg = (c & 7) ^ (row & 7);
      gload_lds16(Ab + (size_t)row * lda + jg * 8, slot + c * 8);
    }
#pragma unroll
    for (int l = 0; l < 4; ++l) {
      const int c = tid + l * 512;
      const int row = c >> 3;
      const int jg = (c & 7) ^ (row & 7);
      gload_lds16(Bb + (size_t)row * ldb + jg * 8, slot + ASZ + c * 8);
    }
  };

  stage(0);
  stage(1);
  wait_vmcnt<6>();
  __builtin_amdgcn_s_barrier();
  __builtin_amdgcn_sched_barrier(0);

  const int r15 = ln & 15;
  const int jk = ln >> 4;
  const int sw0 = ((jk ^ (r15 & 7)) * 8);
  const int sw1 = (((4 + jk) ^ (r15 & 7)) * 8);

  for (int t = 0; t < NT; ++t) {
    if (t + 2 < NT) stage(t + 2);
    const u16* Abuf = lds + (t % 3) * SLOT;
    const u16* Bbuf = Abuf + ASZ;
    bf16x8 a0[4], a1[4], b0[4], b1[4];
#pragma unroll
    for (int j = 0; j < 4; ++j) {
      const int rb = ((wn * 4 + j) * 16 + r15) * 64;
      b0[j] = *(const bf16x8*)(Bbuf + rb + sw0);
      b1[j] = *(const bf16x8*)(Bbuf + rb + sw1);
    }
#pragma unroll
    for (int i = 0; i < 4; ++i) {
      const int ra = ((wm * 4 + i) * 16 + r15) * 64;
      a0[i] = *(const bf16x8*)(Abuf + ra + sw0);
      a1[i] = *(const bf16x8*)(Abuf + ra + sw1);
    }
    __builtin_amdgcn_s_setprio(1);
#pragma unroll
    for (int i = 0; i < 4; ++i)
#pragma unroll
      for (int j = 0; j < 4; ++j) {
        acc[i][j] = __builtin_amdgcn_mfma_f32_16x16x32_bf16(
            a0[i], b0[j], acc[i][j], 0, 0, 0);
        acc[i][j] = __builtin_amdgcn_mfma_f32_16x16x32_bf16(
            a1[i], b1[j], acc[i][j], 0, 0, 0);
      }
    __builtin_amdgcn_s_setprio(0);
    if (t + 1 < NT) {
      if (t + 2 < NT) wait_vmcnt<6>();
      else            wait_vmcnt<0>();
      __builtin_amdgcn_s_barrier();
      __builtin_amdgcn_sched_barrier(0);
    }
  }

  const int orow = (ln >> 4) * 4;
  const int ocol = ln & 15;
#pragma unroll
  for (int mi = 0; mi < 4; ++mi)
#pragma unroll
    for (int ni = 0; ni < 4; ++ni) {
      const int rbase = m0 + wm * 64 + mi * 16 + orow;
      const int cc = n0 + wn * 64 + ni * 16 + ocol;
#pragma unroll
      for (int i = 0; i < 4; ++i) {
        const float v = acc[mi][ni][i];
        const long long off =
            (long long)(rbase + i) * ldc + cc + (long long)z * sC;
        if (STORE == 0) Cf[off] = v;
        else            Ch[off] = f2bf(v);
      }
    }
}

// ===== bf16 GEMM BK=32 (r9-proven) — low tier only.
template <int NSEG, int STORE, int M_REP>
__global__ __launch_bounds__(512, 2) void gemmc(
    const u16* __restrict__ A0, const u16* __restrict__ A1,
    const u16* __restrict__ A2, const u16* __restrict__ B0,
    const u16* __restrict__ B1, const u16* __restrict__ B2,
    float* __restrict__ Cf, u16* __restrict__ Ch, u16* __restrict__ Cl,
    int Kseg, int lda, int ldb, int ldc,
    long long sA, long long sB, long long sC) {
  constexpr int BM = 32 * M_REP;
  constexpr int ASZ = BM * 32;
  constexpr int BSZ = 8192;
  constexpr int SLOT = ASZ + BSZ;
  constexpr int LA = M_REP / 4;
  constexpr int L = LA + 2;
  __shared__ u16 lds[3 * SLOT];

  const int tid = threadIdx.x;
  const int ln = tid & 63;
  const int wid = tid >> 6;
  const int wm = wid >> 2;
  const int wn = wid & 3;
  const int m0 = blockIdx.y * BM;
  const int n0 = blockIdx.x * 256;
  const int z = blockIdx.z;
  const long long za = (long long)z * sA;
  const long long zb = (long long)z * sB;

  const int NT = NSEG * (Kseg >> 5);

  f32x4 acc[M_REP][4];
  const f32x4 zero = {0.f, 0.f, 0.f, 0.f};
#pragma unroll
  for (int i = 0; i < M_REP; i++)
#pragma unroll
    for (int j = 0; j < 4; j++) acc[i][j] = zero;

  auto baseA = [&](int t) -> const u16* {
    int kk = t << 5;
    const u16* p = A0;
    if (NSEG >= 2 && kk >= Kseg) { kk -= Kseg; p = A1; }
    if (NSEG >= 3 && kk >= Kseg) { kk -= Kseg; p = A2; }
    return p + za + (size_t)m0 * lda + kk;
  };
  auto baseB = [&](int t) -> const u16* {
    int kk = t << 5;
    const u16* p = B0;
    if (NSEG >= 2 && kk >= Kseg) { kk -= Kseg; p = B1; }
    if (NSEG >= 3 && kk >= Kseg) { kk -= Kseg; p = B2; }
    return p + zb + (size_t)n0 * ldb + kk;
  };
  auto stage = [&](int t) {
    u16* slot = lds + (t % 3) * SLOT;
    const u16* Ab = baseA(t);
    const u16* Bb = baseB(t);
#pragma unroll
    for (int l = 0; l < LA; ++l) {
      const int c = tid + l * 512;
      const int row = ((c >> 6) << 4) + (c & 15);
      const int kk = ((c >> 4) & 3) * 8;
      gload_lds16(Ab + (size_t)row * lda + kk, slot + c * 8);
    }
#pragma unroll
    for (int l = 0; l < 2; ++l) {
      const int c = tid + l * 512;
      const int row = ((c >> 6) << 4) + (c & 15);
      const int kk = ((c >> 4) & 3) * 8;
      gload_lds16(Bb + (size_t)row * ldb + kk, slot + ASZ + c * 8);
    }
  };

  stage(0);
  stage(1);
  wait_vmcnt<L>();
  __builtin_amdgcn_s_barrier();
  __builtin_amdgcn_sched_barrier(0);

  for (int t = 0; t < NT; ++t) {
    if (t + 2 < NT) stage(t + 2);
    const u16* Abuf = lds + (t % 3) * SLOT;
    const u16* Bbuf = Abuf + ASZ;
    const int fo = ln * 8;
    bf16x8 a[M_REP], b[4];
#pragma unroll
    for (int j = 0; j < 4; ++j)
      b[j] = *(const bf16x8*)(Bbuf + (wn * 4 + j) * 512 + fo);
#pragma unroll
    for (int i = 0; i < M_REP; ++i)
      a[i] = *(const bf16x8*)(Abuf + (wm * M_REP + i) * 512 + fo);
    __builtin_amdgcn_s_setprio(1);
#pragma unroll
    for (int i = 0; i < M_REP; ++i)
#pragma unroll
      for (int j = 0; j < 4; ++j)
        acc[i][j] = __builtin_amdgcn_mfma_f32_16x16x32_bf16(
            a[i], b[j], acc[i][j], 0, 0, 0);
    __builtin_amdgcn_s_setprio(0);
    if (t + 1 < NT) {
      if (t + 2 < NT) wait_vmcnt<L>();
      else            wait_vmcnt<0>();
      __builtin_amdgcn_s_barrier();
      __builtin_amdgcn_sched_barrier(0);
    }
  }

  const int orow = (ln >> 4) * 4;
  const int ocol = ln & 15;
#pragma unroll
  for (int mi = 0; mi < M_REP; ++mi)
#pragma unroll
    for (int ni = 0; ni < 4; ++ni) {
      const int rbase = m0 + wm * (M_REP * 16) + mi * 16 + orow;
      const int cc = n0 + wn * 64 + ni * 16 + ocol;
#pragma unroll
      for (int i = 0; i < 4; ++i) {
        const float v = acc[mi][ni][i];
        const long long off =
            (long long)(rbase + i) * ldc + cc + (long long)z * sC;
        if (STORE == 0) {
          Cf[off] = v;
        } else if (STORE == 1) {
          const u16 h = f2bf(v);
          Ch[off] = h;
          Cl[off] = f2bf(v - bf2f(h));
        } else {
          Ch[off] = f2bf(v);
        }
      }
    }
}

// ---- softmax (row = 2048) ----
__device__ __forceinline__ float blk_max(float v, float* red) {
  const int wv = threadIdx.x >> 6, lnn = threadIdx.x & 63;
#pragma unroll
  for (int off = 32; off; off >>= 1) v = fmaxf(v, __shfl_xor(v, off));
  if (lnn == 0) red[wv] = v;
  __syncthreads();
  return fmaxf(fmaxf(red[0], red[1]), fmaxf(red[2], red[3]));
}
__device__ __forceinline__ float blk_sum(float v, float* red) {
  const int wv = threadIdx.x >> 6, lnn = threadIdx.x & 63;
#pragma unroll
  for (int off = 32; off; off >>= 1) v += __shfl_xor(v, off);
  if (lnn == 0) red[wv] = v;
  __syncthreads();
  return red[0] + red[1] + red[2] + red[3];
}

// f32 L row -> bf16 P in place (row stride stays 4096 u16) [low tier]
__global__ __launch_bounds__(256) void softmax_inplace(float* __restrict__ L) {
  float* p = L + (size_t)blockIdx.x * 2048;
  const int t = threadIdx.x;
  __shared__ float redm[4];
  __shared__ float reds[4];
  float4 x0 = *(const float4*)(p + t * 4);
  float4 x1 = *(const float4*)(p + 1024 + t * 4);
  float m = fmaxf(fmaxf(fmaxf(x0.x, x0.y), fmaxf(x0.z, x0.w)),
                  fmaxf(fmaxf(x1.x, x1.y), fmaxf(x1.z, x1.w)));
  m = blk_max(m, redm);
  float e[8];
  e[0] = __expf(x0.x - m); e[1] = __expf(x0.y - m);
  e[2] = __expf(x0.z - m); e[3] = __expf(x0.w - m);
  e[4] = __expf(x1.x - m); e[5] = __expf(x1.y - m);
  e[6] = __expf(x1.z - m); e[7] = __expf(x1.w - m);
  float s = e[0] + e[1] + e[2] + e[3] + e[4] + e[5] + e[6] + e[7];
  s = blk_sum(s, reds);
  const float inv = 1.f / s;
  u16* q = (u16*)p;
  ushort4 o0, o1;
  o0.x = f2bf(e[0] * inv); o0.y = f2bf(e[1] * inv);
  o0.z = f2bf(e[2] * inv); o0.w = f2bf(e[3] * inv);
  o1.x = f2bf(e[4] * inv); o1.y = f2bf(e[5] * inv);
  o1.z = f2bf(e[6] * inv); o1.w = f2bf(e[7] * inv);
  *(ushort4*)(q + t * 4) = o0;
  *(ushort4*)(q + 1024 + t * 4) = o1;
}

// split-bf16 L (Lh+Ll) -> bf16 P over Lh row (stride 2048 u16)
__global__ __launch_bounds__(256) void softmax_split(
    u16* __restrict__ Lh, const u16* __restrict__ Ll) {
  u16* ph = Lh + (size_t)blockIdx.x * 2048;
  const u16* pl = Ll + (size_t)blockIdx.x * 2048;
  const int t = threadIdx.x;
  __shared__ float redm[4];
  __shared__ float reds[4];
  ushort4 h0 = *(const ushort4*)(ph + t * 4);
  ushort4 h1 = *(const ushort4*)(ph + 1024 + t * 4);
  ushort4 l0 = *(const ushort4*)(pl + t * 4);
  ushort4 l1 = *(const ushort4*)(pl + 1024 + t * 4);
  float x[8];
  x[0] = bf2f(h0.x) + bf2f(l0.x); x[1] = bf2f(h0.y) + bf2f(l0.y);
  x[2] = bf2f(h0.z) + bf2f(l0.z); x[3] = bf2f(h0.w) + bf2f(l0.w);
  x[4] = bf2f(h1.x) + bf2f(l1.x); x[5] = bf2f(h1.y) + bf2f(l1.y);
  x[6] = bf2f(h1.z) + bf2f(l1.z); x[7] = bf2f(h1.w) + bf2f(l1.w);
  float m = fmaxf(fmaxf(fmaxf(x[0], x[1]), fmaxf(x[2], x[3])),
                  fmaxf(fmaxf(x[4], x[5]), fmaxf(x[6], x[7])));
  m = blk_max(m, redm);
  float e[8];
#pragma unroll
  for (int j = 0; j < 8; ++j) e[j] = __expf(x[j] - m);
  float s = e[0] + e[1] + e[2] + e[3] + e[4] + e[5] + e[6] + e[7];
  s = blk_sum(s, reds);
  const float inv = 1.f / s;
  ushort4 o0, o1;
  o0.x = f2bf(e[0] * inv); o0.y = f2bf(e[1] * inv);
  o0.z = f2bf(e[2] * inv); o0.w = f2bf(e[3] * inv);
  o1.x = f2bf(e[4] * inv); o1.y = f2bf(e[5] * inv);
  o1.z = f2bf(e[6] * inv); o1.w = f2bf(e[7] * inv);
  *(ushort4*)(ph + t * 4) = o0;
  *(ushort4*)(ph + 1024 + t * 4) = o1;
}

extern "C" void kernel_launch(void* const* d_in, const int* in_sizes, int n_in,
                              void* d_out, int out_size, void* d_ws, size_t ws_size,
                              hipStream_t stream) {
  constexpr int Bn = 4, S = 2048, D = 1024;
  constexpr long long TOK = (long long)Bn * S;  // 8192
  constexpr long long DD = (long long)D * D;
  const float* X = (const float*)d_in[0];
  const float* Wq = (const float*)d_in[1];
  const float* Wk = (const float*)d_in[2];
  const float* Wv = (const float*)d_in[3];
  float* out = (float*)d_out;
  const dim3 blk(256);
  const dim3 gblk(512);

  char* w = (char*)d_ws;
  auto au16 = [&](long long n) { u16* p = (u16*)w; w += n * 2; return p; };
  auto as8 = [&](long long n) { s8* p = (s8*)w; w += n; return p; };

  if (ws_size >= (size_t)127926272ULL) {
    // Layout (127.93 MB): Xh Xl | Wch Wcl Wvh | QKa QKb (i8) | VT | Ll
    u16* Xh = au16(TOK * D);          // dead after VT -> hosts Lh
    u16* Xl = au16(TOK * D);
    u16* Wch = au16(2 * DD);
    u16* Wcl = au16(2 * DD);
    u16* Wvh = au16(DD);
    s8* QKa = as8(TOK * 2 * D);       // i8 hi plane, cols 0..1023=Q, rest=K
    s8* QKb = as8(TOK * 2 * D);       // i8 lo plane
    u16* VT = au16((long long)D * TOK);  // [1024][8192]
    u16* Ll = au16(TOK * S);          // logit lo plane (tail)
    u16* Lh = (u16*)d_ws;             // logit hi plane over dead X region

    split_f32_kernel<true><<<2048, blk, 0, stream>>>(X, Xh, Xl, TOK * D);
    quantW3_kernel<<<dim3(256, 1, 3), blk, 0, stream>>>(
        Wq, Wk, Wv, Wch, Wcl, Wvh, DD);

    // fused-split Q|K projection -> i8 planes: (8,32) = 256 blocks
    gemmf<<<dim3(8, 32, 1), gblk, 0, stream>>>(
        Xh, Xl, Wch, Wcl, QKa, QKb);
    // VT[e,tok] = Wvh . Xh^T : coalesced BK=64, (32,8) = 256 blocks
    gemmc64<2><<<dim3(32, 8, 1), gblk, 0, stream>>>(
        Wvh, Xh, nullptr, VT, D, D, D, (int)TOK, 0, 0, 0);
    // X region dead now.

    // QKT fused-i8 full-line staging, one z=4 launch: (16,16,4) = 1024 blk
    g2p<<<dim3(16, 16, 4), gblk, 0, stream>>>(
        QKa, QKb, QKa + D, QKb + D, Lh, Ll,
        D, 2 * D, 2 * D, S,
        (long long)S * 2 * D, (long long)S * 2 * D, (long long)S * S,
        3.90625e-3f, 3.0517578125e-5f);
    softmax_split<<<dim3(4 * S), blk, 0, stream>>>(Lh, Ll);
    // O = P . VT^T : coalesced BK=64, (4,16,4) = 256 blocks
    gemmc64<0><<<dim3(4, 16, 4), gblk, 0, stream>>>(
        Lh, VT, out, nullptr, S, S, (int)TOK, D,
        (long long)S * S, (long long)S, (long long)S * D);
  } else {
    // Low tier (~82 MB): per-batch bf16 path (r9/r16)
    u16* Xh = au16(TOK * D);
    u16* Xl = au16(TOK * D);
    u16* Wch = au16(2 * DD);
    u16* Wcl = au16(2 * DD);
    u16* Wvh = au16(DD);
    u16* QKhb = au16((long long)S * 2 * D);
    u16* QKlb = au16((long long)S * 2 * D);
    u16* VTb = au16((long long)D * S);
    float* Lb = (float*)w;

    split_f32_kernel<true><<<2048, blk, 0, stream>>>(X, Xh, Xl, TOK * D);
    split_f32_kernel<true><<<512, blk, 0, stream>>>(Wq, Wch, Wcl, DD);
    split_f32_kernel<true><<<512, blk, 0, stream>>>(Wk, Wch + DD, Wcl + DD, DD);
    split_f32_kernel<false><<<512, blk, 0, stream>>>(Wv, Wvh, nullptr, DD);

    for (int b = 0; b < Bn; ++b) {
      const long long xo = (long long)b * S * D;
      gemmc<3, 1, 8><<<dim3(8, 8, 1), gblk, 0, stream>>>(
          Xh + xo, Xh + xo, Xl + xo, Wch, Wcl, Wch, nullptr, QKhb, QKlb,
          D, D, D, 2 * D, 0, 0, 0);
      gemmc<1, 2, 4><<<dim3(8, 8, 1), gblk, 0, stream>>>(
          Wvh, nullptr, nullptr, Xh + xo, nullptr, nullptr, nullptr, VTb,
          nullptr, D, D, D, S, 0, 0, 0);
      gemmc<3, 0, 4><<<dim3(8, 16, 1), gblk, 0, stream>>>(
          QKhb, QKhb, QKlb, QKhb + D, QKlb + D, QKhb + D,
          Lb, nullptr, nullptr, D, 2 * D, 2 * D, S, 0, 0, 0);
      softmax_inplace<<<dim3(S), blk, 0, stream>>>(Lb);
      gemmc<1, 0, 4><<<dim3(4, 16, 1), gblk, 0, stream>>>(
          (const u16*)Lb, nullptr, nullptr, VTb, nullptr, nullptr,
          out + xo, nullptr, nullptr, S, 2 * S, S, D, 0, 0, 0);
    }
  }
}